// Round 2
// baseline (1274.541 us; speedup 1.0000x reference)
//
#include <hip/hip_runtime.h>

// GPT forward, MI355X gfx950.
// Shapes: V=371 E=512 H=8 L=8 B=4 T=1024 D=64, N=B*T=4096.
// Inputs float32 (runtime-detected, bf16 supported); output matches input fmt.
// r11: gemm_gl v2 — 2-phase double-buffered global_load_lds pipeline (T3
// minimal recipe): STAGE(next) issued before COMPUTE(cur); counted waits via
// inline-asm s_waitcnt vmcnt(0) + raw s_barrier (NOT __syncthreads, which
// drains everything before the loads can overlap). r10's no-pipeline version
// exposed full load latency per k-step (MfmaUtil 5%).

#define VOCAB 371
#define VPAD  384
#define EMB   512
#define NH    8
#define NL    8
#define TS    1024
#define NTOK  4096
#define NEG_INF (-1e30f)

typedef unsigned short ushort_t;
typedef __attribute__((ext_vector_type(8))) short short8;
typedef __attribute__((ext_vector_type(4))) float f32x4;

__device__ inline float bf2f(ushort_t b) {
    unsigned int u = ((unsigned int)b) << 16;
    float f; __builtin_memcpy(&f, &u, 4); return f;
}
__device__ inline ushort_t f2bf(float f) {
    unsigned int u; __builtin_memcpy(&u, &f, 4);
    u = (u + 0x7fff + ((u >> 16) & 1)) >> 16;   // RNE
    return (ushort_t)u;
}

// async global->LDS, 16B per lane. LDS dest must be wave-uniform base; lane l
// lands at base + l*16B. Size arg must be a literal.
#define GLOAD16(gp, lp) __builtin_amdgcn_global_load_lds( \
        (__attribute__((address_space(1))) void*)(gp), \
        (__attribute__((address_space(3))) void*)(lp), 16, 0, 0)

// ---------------- dtype probe ---------------------------------------------------
__global__ __launch_bounds__(64) void detect_k(const ushort_t* __restrict__ w,
        int* __restrict__ flag)
{
    int i = threadIdx.x;
    float v = bf2f(w[2 * i]);
    bool ok = (__builtin_fabsf(v) <= 4.0f);
    unsigned long long m = __ballot(ok);
    if (i == 0) flag[0] = (__popcll(m) >= 56) ? 1 : 0;   // 1 = bf16, 0 = float32
}

// ---------------- ws-too-small sentinel ----------------------------------------
__global__ __launch_bounds__(256) void sentinel_k(ushort_t* __restrict__ out, int n)
{
    int i = blockIdx.x * 256 + threadIdx.x;
    if (i < n) out[i] = 0x447A;
}

// ---------------- embedding ----------------------------------------------------
__global__ __launch_bounds__(256) void embed_k(const int* __restrict__ idx,
        const void* __restrict__ wte, const void* __restrict__ wpe,
        float* __restrict__ x, const int* __restrict__ flag)
{
    int n = blockIdx.x, tid = threadIdx.x;
    int t = n & (TS - 1);
    int v = idx[n];
    size_t o = (size_t)n * EMB;
    float a0, a1, b0, b1;
    if (*flag) {
        const ushort_t* te = (const ushort_t*)wte; const ushort_t* pe = (const ushort_t*)wpe;
        a0 = bf2f(te[v * EMB + tid]); a1 = bf2f(te[v * EMB + 256 + tid]);
        b0 = bf2f(pe[t * EMB + tid]); b1 = bf2f(pe[t * EMB + 256 + tid]);
    } else {
        const float* te = (const float*)wte; const float* pe = (const float*)wpe;
        a0 = te[v * EMB + tid]; a1 = te[v * EMB + 256 + tid];
        b0 = pe[t * EMB + tid]; b1 = pe[t * EMB + 256 + tid];
    }
    x[o + tid] = a0 + b0;
    x[o + 256 + tid] = a1 + b1;
}

// ---------------- layernorm v2: one wave per row, no barriers ------------------
__global__ __launch_bounds__(256) void ln_k(const float* __restrict__ x,
        const void* __restrict__ w, long woff, ushort_t* __restrict__ out,
        const int* __restrict__ flag)
{
    const int row = blockIdx.x * 4 + (threadIdx.x >> 6);
    const int lane = threadIdx.x & 63;
    const float* xr = x + (size_t)row * EMB + lane * 8;
    float4 f0 = *(const float4*)xr;
    float4 f1 = *(const float4*)(xr + 4);
    float v[8] = {f0.x, f0.y, f0.z, f0.w, f1.x, f1.y, f1.z, f1.w};
    float s = ((v[0] + v[1]) + (v[2] + v[3])) + ((v[4] + v[5]) + (v[6] + v[7]));
#pragma unroll
    for (int off = 32; off > 0; off >>= 1) s += __shfl_xor(s, off, 64);
    float mean = s * (1.0f / EMB);
    float s2 = 0.f;
#pragma unroll
    for (int j = 0; j < 8; ++j) { v[j] -= mean; s2 += v[j] * v[j]; }
#pragma unroll
    for (int off = 32; off > 0; off >>= 1) s2 += __shfl_xor(s2, off, 64);
    float rs = rsqrtf(s2 * (1.0f / EMB) + 1e-5f);
    float g[8];
    if (*flag) {
        const ushort_t* wb = (const ushort_t*)w + woff + lane * 8;
        ushort_t tmp[8];
        *(uint4*)tmp = *(const uint4*)wb;
#pragma unroll
        for (int j = 0; j < 8; ++j) g[j] = bf2f(tmp[j]);
    } else {
        const float* wf = (const float*)w + woff + lane * 8;
        float4 g0 = *(const float4*)wf;
        float4 g1 = *(const float4*)(wf + 4);
        g[0] = g0.x; g[1] = g0.y; g[2] = g0.z; g[3] = g0.w;
        g[4] = g1.x; g[5] = g1.y; g[6] = g1.z; g[7] = g1.w;
    }
    ushort_t ob[8];
#pragma unroll
    for (int j = 0; j < 8; ++j) ob[j] = f2bf(v[j] * rs * g[j]);
    *(uint4*)(out + (size_t)row * EMB + lane * 8) = *(uint4*)ob;
}

// ---------------- weight transpose v3: [K,N] dtype -> bf16 [N,K] ---------------
__global__ __launch_bounds__(256) void wtrans_k(const void* __restrict__ aw,
        const void* __restrict__ pw, const void* __restrict__ fw,
        const void* __restrict__ fpw, long l, ushort_t* __restrict__ wbuf,
        const int* __restrict__ flag)
{
    __shared__ float tile[64][65];
    const int isbf = *flag;
    long lay = (l < 0) ? (long)blockIdx.z : l;
    ushort_t* obase = wbuf + ((l < 0) ? (size_t)blockIdx.z * 3145728 : 0);
    int t = blockIdx.x;
    const void* src; ushort_t* dst; int Kw, Nw; long ioff;
    if (t < 192)      { src = aw;  dst = obase;           Kw = 512;  Nw = 1536; ioff = lay * 512L * 1536; }
    else if (t < 256) { t -= 192; src = pw;  dst = obase + 786432;  Kw = 512;  Nw = 512;  ioff = lay * 512L * 512; }
    else if (t < 512) { t -= 256; src = fw;  dst = obase + 1048576; Kw = 512;  Nw = 2048; ioff = lay * 512L * 2048; }
    else              { t -= 512; src = fpw; dst = obase + 2097152; Kw = 2048; Nw = 512;  ioff = lay * 2048L * 512; }
    int tn = Nw >> 6;
    int n0 = (t % tn) * 64, k0 = (t / tn) * 64;
    const int r = threadIdx.x >> 2, cq = (threadIdx.x & 3) * 16;
    size_t ii = ioff + (size_t)(k0 + r) * Nw + n0 + cq;
    if (isbf) {
        const ushort_t* sb = (const ushort_t*)src + ii;
        ushort_t tmp[16];
        *(uint4*)tmp = *(const uint4*)sb;
        *(uint4*)(tmp + 8) = *(const uint4*)(sb + 8);
#pragma unroll
        for (int j = 0; j < 16; ++j) tile[r][cq + j] = bf2f(tmp[j]);
    } else {
        const float* sf = (const float*)src + ii;
        *(float4*)&tile[r][cq]      = *(const float4*)sf;
        *(float4*)&tile[r][cq + 4]  = *(const float4*)(sf + 4);
        *(float4*)&tile[r][cq + 8]  = *(const float4*)(sf + 8);
        *(float4*)&tile[r][cq + 12] = *(const float4*)(sf + 12);
    }
    __syncthreads();
    const int kc = (threadIdx.x & 7) * 8;
#pragma unroll
    for (int j = 0; j < 2; ++j) {
        const int n = (threadIdx.x >> 3) + j * 32;
        unsigned pk[4];
#pragma unroll
        for (int i = 0; i < 4; ++i) {
            unsigned lo = f2bf(tile[kc + 2 * i][n]);
            unsigned hi = f2bf(tile[kc + 2 * i + 1][n]);
            pk[i] = lo | (hi << 16);
        }
        *(uint4*)(dst + (size_t)(n0 + n) * Kw + k0 + kc) = *(uint4*)pk;
    }
}

// ---------------- wte convert (zero-padded to VPAD rows) -----------------------
__global__ __launch_bounds__(256) void wconv_k(const void* __restrict__ in,
        ushort_t* __restrict__ out, int n, int nreal, const int* __restrict__ flag)
{
    int i = blockIdx.x * 256 + threadIdx.x;
    if (i >= n) return;
    ushort_t v = 0;
    if (i < nreal) v = (*flag) ? ((const ushort_t*)in)[i] : f2bf(((const float*)in)[i]);
    out[i] = v;
}

// ---------------- 2-phase dbuf NT GEMM: BMx64, BK=64, global_load_lds ----------
// MI = m-fragments per wave (BM = MI*64). Double-buffered linear LDS; next
// tile's global_load_lds issued BEFORE current tile's ds_read+MFMA; one
// inline-asm vmcnt(0) + raw s_barrier per k-step AFTER the MFMAs, so the
// in-flight loads overlap compute. Correctness: every ds_read is consumed by
// an MFMA before the barrier (compiler-inserted lgkmcnt), so no wave crosses
// with pending reads of the buffer the next STAGE overwrites.
template<int MI>
__global__ __launch_bounds__(256) void gemm_gl(const ushort_t* __restrict__ A,
        const ushort_t* __restrict__ Bt, int M, int N, int K,
        float* __restrict__ outF, ushort_t* __restrict__ outB, void* __restrict__ outD,
        const float* __restrict__ res, int act, const int* __restrict__ flag)
{
    constexpr int BM = MI * 64;
    __shared__ __align__(16) ushort_t Al[2][BM * 64];
    __shared__ __align__(16) ushort_t Bl[2][64 * 64];
    const int tid = threadIdx.x;
    const int wave = tid >> 6, lane = tid & 63;
    const int quad = lane >> 4, l16 = lane & 15;
    const int m0 = blockIdx.y * BM, n0 = blockIdx.x * 64;
    const int sr = lane >> 3, sc = (lane & 7) * 8;
    const size_t K8 = (size_t)K * 8;
    const ushort_t* Ag = A + (size_t)(m0 + wave * (MI * 16) + sr) * K + sc;
    const ushort_t* Bg = Bt + (size_t)(n0 + wave * 16 + sr) * K + sc;
    const int awoff = (wave * (MI * 16)) * 64;
    const int bwoff = (wave * 16) * 64;
    f32x4 acc[MI][4] = {};

#define STAGE_GL(buf, k0) do { \
        _Pragma("unroll") \
        for (int i = 0; i < MI * 2; ++i) \
            GLOAD16(Ag + (k0) + (size_t)i * K8, &Al[buf][awoff + i * 512]); \
        _Pragma("unroll") \
        for (int i = 0; i < 2; ++i) \
            GLOAD16(Bg + (k0) + (size_t)i * K8, &Bl[buf][bwoff + i * 512]); \
    } while (0)

#define COMPUTE_GL(buf) do { \
        _Pragma("unroll") \
        for (int ks = 0; ks < 2; ++ks) { \
            short8 af[MI], bfr[4]; \
            _Pragma("unroll") \
            for (int mi = 0; mi < MI; ++mi) \
                af[mi] = *(const short8*)&Al[buf][(wave * (MI * 16) + mi * 16 + l16) * 64 + ks * 32 + quad * 8]; \
            _Pragma("unroll") \
            for (int ni = 0; ni < 4; ++ni) \
                bfr[ni] = *(const short8*)&Bl[buf][(ni * 16 + l16) * 64 + ks * 32 + quad * 8]; \
            _Pragma("unroll") \
            for (int mi = 0; mi < MI; ++mi) \
                _Pragma("unroll") \
                for (int ni = 0; ni < 4; ++ni) \
                    acc[mi][ni] = __builtin_amdgcn_mfma_f32_16x16x32_bf16( \
                            af[mi], bfr[ni], acc[mi][ni], 0, 0, 0); \
        } \
    } while (0)

    STAGE_GL(0, 0);
    asm volatile("s_waitcnt vmcnt(0)" ::: "memory");
    __builtin_amdgcn_s_barrier();
    const int nk = K >> 6;
    int cur = 0;
    for (int t = 0; t < nk - 1; ++t) {
        STAGE_GL(cur ^ 1, (t + 1) << 6);   // async loads into other buffer
        COMPUTE_GL(cur);                    // overlaps the in-flight loads
        asm volatile("s_waitcnt vmcnt(0)" ::: "memory");
        __builtin_amdgcn_s_barrier();
        cur ^= 1;
    }
    COMPUTE_GL(cur);
#undef STAGE_GL
#undef COMPUTE_GL

    const int isbf = *flag;
#pragma unroll
    for (int mi = 0; mi < MI; ++mi) {
        const int rowb = m0 + wave * (MI * 16) + mi * 16 + quad * 4;
#pragma unroll
        for (int ni = 0; ni < 4; ++ni) {
            const int nn = n0 + ni * 16 + l16;
            if (nn >= N) continue;
#pragma unroll
            for (int r = 0; r < 4; ++r) {
                size_t o = (size_t)(rowb + r) * N + nn;
                float v = acc[mi][ni][r];
                if (res) v += res[o];
                if (act) v = 0.5f * v * (1.0f + erff(v * 0.70710678118f));
                if (outF)      outF[o] = v;
                else if (outB) outB[o] = f2bf(v);
                else if (isbf) ((ushort_t*)outD)[o] = f2bf(v);
                else           ((float*)outD)[o] = v;
            }
        }
    }
}

// ---------------- legacy GEMM (fallback) ---------------------------------------
__global__ __launch_bounds__(256) void gemm_k(const ushort_t* __restrict__ A,
        const void* __restrict__ B, long boff, int M, int N, int K, int bt,
        float* __restrict__ outF, ushort_t* __restrict__ outB, void* __restrict__ outD,
        const float* __restrict__ res, int act, const int* __restrict__ flag)
{
    __shared__ ushort_t Al[64 * 40];
    __shared__ ushort_t Bl[64 * 40];
    const int isbf = *flag;
    const int tid = threadIdx.x;
    const int wave = tid >> 6, lane = tid & 63;
    const int quad = lane >> 4, l16 = lane & 15;
    const int m0 = blockIdx.y * 64, n0 = blockIdx.x * 64;
    const int sr = tid >> 2, sc = (tid & 3) * 8;
    const int kr = tid >> 3, nc = (tid & 7) * 8;
    f32x4 acc[4] = {};
    const bool bok = (n0 + sr) < N;
    const ushort_t* Ag = A + (size_t)(m0 + sr) * K + sc;
    const ushort_t* Bb = (const ushort_t*)B + boff;
    const float*    Bf = (const float*)B + boff;
    const size_t i1 = (size_t)(n0 + sr) * K + sc;
    const size_t i0 = (size_t)kr * N + n0 + nc;
    for (int k0 = 0; k0 < K; k0 += 32) {
        uint4 av = *(const uint4*)(Ag + k0);
        ushort_t b8[8] = {0, 0, 0, 0, 0, 0, 0, 0};
        size_t bi = bt ? (i1 + k0) : (i0 + (size_t)k0 * N);
        if (!bt || bok) {
            if (isbf) *(uint4*)b8 = *(const uint4*)(Bb + bi);
            else {
                float4 f0 = *(const float4*)(Bf + bi);
                float4 f1 = *(const float4*)(Bf + bi + 4);
                b8[0] = f2bf(f0.x); b8[1] = f2bf(f0.y); b8[2] = f2bf(f0.z); b8[3] = f2bf(f0.w);
                b8[4] = f2bf(f1.x); b8[5] = f2bf(f1.y); b8[6] = f2bf(f1.z); b8[7] = f2bf(f1.w);
            }
        }
        __syncthreads();
        *(uint4*)&Al[sr * 40 + sc] = av;
        if (bt) *(uint4*)&Bl[sr * 40 + sc] = *(uint4*)b8;
        else {
#pragma unroll
            for (int i = 0; i < 8; ++i) Bl[(nc + i) * 40 + kr] = b8[i];
        }
        __syncthreads();
        short8 af = *(const short8*)&Al[(wave * 16 + l16) * 40 + quad * 8];
#pragma unroll
        for (int nt = 0; nt < 4; ++nt) {
            short8 bf = *(const short8*)&Bl[(nt * 16 + l16) * 40 + quad * 8];
            acc[nt] = __builtin_amdgcn_mfma_f32_16x16x32_bf16(af, bf, acc[nt], 0, 0, 0);
        }
    }
    const int mb = m0 + wave * 16 + quad * 4;
#pragma unroll
    for (int nt = 0; nt < 4; ++nt) {
        int nn = n0 + nt * 16 + l16;
        if (nn >= N) continue;
#pragma unroll
        for (int r = 0; r < 4; ++r) {
            size_t o = (size_t)(mb + r) * N + nn;
            float v = acc[nt][r];
            if (res) v += res[o];
            if (act) v = 0.5f * v * (1.0f + erff(v * 0.70710678118f));
            if (outF)      outF[o] = v;
            else if (outB) outB[o] = f2bf(v);
            else if (isbf) ((ushort_t*)outD)[o] = f2bf(v);
            else           ((float*)outD)[o] = v;
        }
    }
}

// ---------------- flash attention v4 (causal), 64-key tiles --------------------
__global__ __launch_bounds__(256) void attn_k(const ushort_t* __restrict__ qkv,
        ushort_t* __restrict__ y)
{
    __shared__ ushort_t Kl[64 * 72];
    __shared__ ushort_t Vt[64 * 72];
    __shared__ ushort_t Pl[4][16 * 72];
    const int tid = threadIdx.x, wave = tid >> 6, lane = tid & 63;
    const int quad = lane >> 4, l16 = lane & 15;
    const int qt = (int)gridDim.x - 1 - blockIdx.x;
    const int b = blockIdx.y >> 3, h = blockIdx.y & 7;
    const int q0b = qt * 64;
    const int q0w = q0b + wave * 16;
    const size_t rstr = 3 * EMB;
    const ushort_t* qbase = qkv + ((size_t)(b * TS) + q0w + l16) * rstr + h * 64;
    short8 qf0, qf1;
    {   // load Q and pre-scale by 1/8 (exact in bf16)
        ushort_t q0[8], q1[8];
        *(uint4*)q0 = *(const uint4*)(qbase + quad * 8);
        *(uint4*)q1 = *(const uint4*)(qbase + 32 + quad * 8);
#pragma unroll
        for (int i = 0; i < 8; ++i) {
            qf0[i] = (short)f2bf(bf2f(q0[i]) * 0.125f);
            qf1[i] = (short)f2bf(bf2f(q1[i]) * 0.125f);
        }
    }
    short8 onesf;
#pragma unroll
    for (int i = 0; i < 8; ++i) onesf[i] = (short)0x3F80;   // bf16 1.0
    f32x4 O[4] = {};
    f32x4 lacc = {};
    const int sk = tid >> 2, sdc = (tid & 3) * 16;
    const int vp = tid >> 3, vdc = (tid & 7) * 8;
    const int vsh = 16 * ((tid & 7) & 3);
    const int vcol = (2 * vp + vsh) & 63;
    for (int kt = 0; kt <= qt; ++kt) {
        const int k0 = kt * 64;
        const ushort_t* krow = qkv + ((size_t)(b * TS) + k0 + sk) * rstr + EMB + h * 64 + sdc;
        uint4 kv0 = *(const uint4*)krow;
        uint4 kv1 = *(const uint4*)(krow + 8);
        const ushort_t* vrow = qkv + ((size_t)(b * TS) + k0 + 2 * vp) * rstr + 2 * EMB + h * 64 + vdc;
        uint4 vv0 = *(const uint4*)vrow;
        uint4 vv1 = *(const uint4*)(vrow + rstr);
        __syncthreads();
        *(uint4*)&Kl[sk * 72 + sdc]     = kv0;
        *(uint4*)&Kl[sk * 72 + sdc + 8] = kv1;
        {
            ushort_t v0[8], v1[8];
            *(uint4*)v0 = vv0; *(uint4*)v1 = vv1;
#pragma unroll
            for (int i = 0; i < 8; ++i) {
                unsigned pk = (unsigned)v0[i] | ((unsigned)v1[i] << 16);
                *(unsigned*)&Vt[(vdc + i) * 72 + vcol] = pk;
            }
        }
        __syncthreads();
        if (kt < qt) {                                 // bulk tile: no masking
            f32x4 S[4] = {};
#pragma unroll
            for (int nt = 0; nt < 4; ++nt) {
                short8 kf0 = *(const short8*)&Kl[(nt * 16 + l16) * 72 + quad * 8];
                short8 kf1 = *(const short8*)&Kl[(nt * 16 + l16) * 72 + 32 + quad * 8];
                S[nt] = __builtin_amdgcn_mfma_f32_16x16x32_bf16(qf0, kf0, S[nt], 0, 0, 0);
                S[nt] = __builtin_amdgcn_mfma_f32_16x16x32_bf16(qf1, kf1, S[nt], 0, 0, 0);
            }
#pragma unroll
            for (int nt = 0; nt < 4; ++nt)
#pragma unroll
                for (int r = 0; r < 4; ++r)
                    Pl[wave][(quad * 4 + r) * 72 + nt * 16 + l16] = f2bf(__expf(S[nt][r]));
        } else {                                       // diagonal tile: masked
            f32x4 S[4] = {};
#pragma unroll
            for (int nt = 0; nt < 4; ++nt) {
                if (nt > wave) continue;
                short8 kf0 = *(const short8*)&Kl[(nt * 16 + l16) * 72 + quad * 8];
                short8 kf1 = *(const short8*)&Kl[(nt * 16 + l16) * 72 + 32 + quad * 8];
                S[nt] = __builtin_amdgcn_mfma_f32_16x16x32_bf16(qf0, kf0, S[nt], 0, 0, 0);
                S[nt] = __builtin_amdgcn_mfma_f32_16x16x32_bf16(qf1, kf1, S[nt], 0, 0, 0);
            }
#pragma unroll
            for (int nt = 0; nt < 4; ++nt)
#pragma unroll
                for (int r = 0; r < 4; ++r) {
                    bool live = (nt < wave) || (nt == wave && l16 <= quad * 4 + r);
                    float p = live ? __expf(S[nt][r]) : 0.f;
                    Pl[wave][(quad * 4 + r) * 72 + nt * 16 + l16] = f2bf(p);
                }
        }
#pragma unroll
        for (int kc = 0; kc < 2; ++kc) {
            short8 pf = *(const short8*)&Pl[wave][l16 * 72 + kc * 32 + quad * 8];
            lacc = __builtin_amdgcn_mfma_f32_16x16x32_bf16(pf, onesf, lacc, 0, 0, 0);
#pragma unroll
            for (int dt = 0; dt < 4; ++dt) {
                int d = dt * 16 + l16;
                int sh = ((2 * dt + (l16 >> 3)) & 3) * 16;
                int col = (kc * 32 + quad * 8 + sh) & 63;
                short8 vf = *(const short8*)&Vt[d * 72 + col];
                O[dt] = __builtin_amdgcn_mfma_f32_16x16x32_bf16(pf, vf, O[dt], 0, 0, 0);
            }
        }
    }
#pragma unroll
    for (int dt = 0; dt < 4; ++dt)
#pragma unroll
        for (int r = 0; r < 4; ++r) {
            int q = q0w + quad * 4 + r;
            float v = O[dt][r] / lacc[r];
            y[((size_t)(b * TS) + q) * EMB + h * 64 + dt * 16 + l16] = f2bf(v);
        }
}

// ---------------- host ---------------------------------------------------------
extern "C" void kernel_launch(void* const* d_in, const int* in_sizes, int n_in,
                              void* d_out, int out_size, void* d_ws, size_t ws_size,
                              hipStream_t stream)
{
    const int*  idx    = (const int*)d_in[0];
    const void* wte    = d_in[1];
    const void* wpe    = d_in[2];
    const void* attn_w = d_in[3];   // [L,512,1536]
    const void* proj_w = d_in[4];   // [L,512,512]
    const void* fc_w   = d_in[5];   // [L,512,2048]
    const void* fcp_w  = d_in[6];   // [L,2048,512]
    const void* ln1_w  = d_in[7];
    const void* ln2_w  = d_in[8];
    const void* lnf_w  = d_in[9];

    const size_t sz_xw    = (size_t)NTOK * EMB * 4;
    const size_t sz_hbf   = (size_t)NTOK * EMB * 2;
    const size_t sz_big   = (size_t)NTOK * 2048 * 2;
    const size_t sz_wteb  = (size_t)VPAD * EMB * 2;
    const size_t sz_wbuf1 = (size_t)3145728 * 2;
    const size_t need_legacy = 256 + sz_xw + sz_hbf + sz_big;
    const size_t need_fast   = need_legacy + sz_wteb + sz_wbuf1;
    const size_t need_all    = need_legacy + sz_wteb + NL * sz_wbuf1;   // ~80 MB

    if (ws_size < need_legacy) {
        sentinel_k<<<(out_size + 255) / 256, 256, 0, stream>>>((ushort_t*)d_out, out_size);
        return;
    }
    int* flag = (int*)d_ws;
    char* p = (char*)d_ws + 256;
    float*    xw  = (float*)p;    p += sz_xw;
    ushort_t* hbf = (ushort_t*)p; p += sz_hbf;
    ushort_t* big = (ushort_t*)p; p += sz_big;

    detect_k<<<1, 64, 0, stream>>>((const ushort_t*)wte, flag);
    embed_k<<<NTOK, 256, 0, stream>>>(idx, wte, wpe, xw, flag);

    if (ws_size >= need_fast) {
        ushort_t* wteb = (ushort_t*)p; p += sz_wteb;
        ushort_t* wbuf = (ushort_t*)p;
        const bool allw = (ws_size >= need_all);
        wconv_k<<<(VPAD * EMB + 255) / 256, 256, 0, stream>>>(wte, wteb,
                VPAD * EMB, VOCAB * EMB, flag);
        if (allw)
            wtrans_k<<<dim3(768, 1, NL), 256, 0, stream>>>(attn_w, proj_w, fc_w, fcp_w,
                    -1, wbuf, flag);
        for (int l = 0; l < NL; ++l) {
            ushort_t* wb = allw ? (wbuf + (size_t)l * 3145728) : wbuf;
            if (!allw)
                wtrans_k<<<dim3(768, 1, 1), 256, 0, stream>>>(attn_w, proj_w, fc_w, fcp_w,
                        (long)l, wbuf, flag);
            ln_k<<<NTOK / 4, 256, 0, stream>>>(xw, ln1_w, (long)l * EMB, hbf, flag);
            gemm_gl<2><<<dim3(24, 32), 256, 0, stream>>>(hbf, wb,
                    NTOK, 1536, 512, nullptr, big, nullptr, nullptr, 0, flag);
            attn_k<<<dim3(16, 32), 256, 0, stream>>>(big, hbf);
            gemm_gl<1><<<dim3(8, 64), 256, 0, stream>>>(hbf, wb + 786432,
                    NTOK, 512, 512, xw, nullptr, nullptr, xw, 0, flag);
            ln_k<<<NTOK / 4, 256, 0, stream>>>(xw, ln2_w, (long)l * EMB, hbf, flag);
            gemm_gl<2><<<dim3(32, 32), 256, 0, stream>>>(hbf, wb + 1048576,
                    NTOK, 2048, 512, nullptr, big, nullptr, nullptr, 1 /*gelu*/, flag);
            gemm_gl<1><<<dim3(8, 64), 256, 0, stream>>>(big, wb + 2097152,
                    NTOK, 512, 2048, xw, nullptr, nullptr, xw, 0, flag);
        }
        ln_k<<<NTOK / 4, 256, 0, stream>>>(xw, lnf_w, 0, hbf, flag);
        gemm_gl<1><<<dim3(6, 64), 256, 0, stream>>>(hbf, wteb,
                NTOK, VOCAB, 512, nullptr, nullptr, d_out, nullptr, 0, flag);
    } else {
        for (int l = 0; l < NL; ++l) {
            ln_k<<<NTOK / 4, 256, 0, stream>>>(xw, ln1_w, (long)l * EMB, hbf, flag);
            gemm_k<<<dim3(24, 64), 256, 0, stream>>>(hbf, attn_w, (long)l * 512 * 1536,
                    NTOK, 1536, 512, 0, nullptr, big, nullptr, nullptr, 0, flag);
            attn_k<<<dim3(16, 32), 256, 0, stream>>>(big, hbf);
            gemm_k<<<dim3(8, 64), 256, 0, stream>>>(hbf, proj_w, (long)l * 512 * 512,
                    NTOK, 512, 512, 0, xw, nullptr, nullptr, xw, 0, flag);
            ln_k<<<NTOK / 4, 256, 0, stream>>>(xw, ln2_w, (long)l * EMB, hbf, flag);
            gemm_k<<<dim3(32, 64), 256, 0, stream>>>(hbf, fc_w, (long)l * 512 * 2048,
                    NTOK, 2048, 512, 0, nullptr, big, nullptr, nullptr, 1, flag);
            gemm_k<<<dim3(8, 64), 256, 0, stream>>>(big, fcp_w, (long)l * 2048 * 512,
                    NTOK, 512, 2048, 0, xw, nullptr, nullptr, xw, 0, flag);
        }
        ln_k<<<NTOK / 4, 256, 0, stream>>>(xw, lnf_w, 0, hbf, flag);
        gemm_k<<<dim3(6, 64), 256, 0, stream>>>(hbf, wte, 0,
                NTOK, VOCAB, 512, 1, nullptr, nullptr, d_out, nullptr, 0, flag);
    }
}

// Round 3
// 1164.429 us; speedup vs baseline: 1.0946x; 1.0946x over previous
//
#include <hip/hip_runtime.h>

// GPT forward, MI355X gfx950.
// Shapes: V=371 E=512 H=8 L=8 B=4 T=1024 D=64, N=B*T=4096.
// Inputs float32 (runtime-detected, bf16 supported); output matches input fmt.
// r12: gemm_gl v3 — STATIC double-buffer pipeline. r11 used Al[2][..] with a
// runtime buffer index; the memory legalizer can't disambiguate LDS stores
// (global_load_lds) from ds_reads of "the other" buffer, so it inserted a
// vmcnt(0) drain before the ds_reads and the pipeline never engaged. Fix:
// four distinct __shared__ objects + x2-unrolled loop with compile-time
// phase. One s_waitcnt vmcnt(0) + s_barrier per k-step AFTER the MFMAs.

#define VOCAB 371
#define VPAD  384
#define EMB   512
#define NH    8
#define NL    8
#define TS    1024
#define NTOK  4096
#define NEG_INF (-1e30f)

typedef unsigned short ushort_t;
typedef __attribute__((ext_vector_type(8))) short short8;
typedef __attribute__((ext_vector_type(4))) float f32x4;

__device__ inline float bf2f(ushort_t b) {
    unsigned int u = ((unsigned int)b) << 16;
    float f; __builtin_memcpy(&f, &u, 4); return f;
}
__device__ inline ushort_t f2bf(float f) {
    unsigned int u; __builtin_memcpy(&u, &f, 4);
    u = (u + 0x7fff + ((u >> 16) & 1)) >> 16;   // RNE
    return (ushort_t)u;
}

// async global->LDS, 16B per lane. LDS dest must be wave-uniform base; lane l
// lands at base + l*16B. Size arg must be a literal.
#define GLOAD16(gp, lp) __builtin_amdgcn_global_load_lds( \
        (__attribute__((address_space(1))) void*)(gp), \
        (__attribute__((address_space(3))) void*)(lp), 16, 0, 0)

// ---------------- dtype probe ---------------------------------------------------
__global__ __launch_bounds__(64) void detect_k(const ushort_t* __restrict__ w,
        int* __restrict__ flag)
{
    int i = threadIdx.x;
    float v = bf2f(w[2 * i]);
    bool ok = (__builtin_fabsf(v) <= 4.0f);
    unsigned long long m = __ballot(ok);
    if (i == 0) flag[0] = (__popcll(m) >= 56) ? 1 : 0;   // 1 = bf16, 0 = float32
}

// ---------------- ws-too-small sentinel ----------------------------------------
__global__ __launch_bounds__(256) void sentinel_k(ushort_t* __restrict__ out, int n)
{
    int i = blockIdx.x * 256 + threadIdx.x;
    if (i < n) out[i] = 0x447A;
}

// ---------------- embedding ----------------------------------------------------
__global__ __launch_bounds__(256) void embed_k(const int* __restrict__ idx,
        const void* __restrict__ wte, const void* __restrict__ wpe,
        float* __restrict__ x, const int* __restrict__ flag)
{
    int n = blockIdx.x, tid = threadIdx.x;
    int t = n & (TS - 1);
    int v = idx[n];
    size_t o = (size_t)n * EMB;
    float a0, a1, b0, b1;
    if (*flag) {
        const ushort_t* te = (const ushort_t*)wte; const ushort_t* pe = (const ushort_t*)wpe;
        a0 = bf2f(te[v * EMB + tid]); a1 = bf2f(te[v * EMB + 256 + tid]);
        b0 = bf2f(pe[t * EMB + tid]); b1 = bf2f(pe[t * EMB + 256 + tid]);
    } else {
        const float* te = (const float*)wte; const float* pe = (const float*)wpe;
        a0 = te[v * EMB + tid]; a1 = te[v * EMB + 256 + tid];
        b0 = pe[t * EMB + tid]; b1 = pe[t * EMB + 256 + tid];
    }
    x[o + tid] = a0 + b0;
    x[o + 256 + tid] = a1 + b1;
}

// ---------------- layernorm v2: one wave per row, no barriers ------------------
__global__ __launch_bounds__(256) void ln_k(const float* __restrict__ x,
        const void* __restrict__ w, long woff, ushort_t* __restrict__ out,
        const int* __restrict__ flag)
{
    const int row = blockIdx.x * 4 + (threadIdx.x >> 6);
    const int lane = threadIdx.x & 63;
    const float* xr = x + (size_t)row * EMB + lane * 8;
    float4 f0 = *(const float4*)xr;
    float4 f1 = *(const float4*)(xr + 4);
    float v[8] = {f0.x, f0.y, f0.z, f0.w, f1.x, f1.y, f1.z, f1.w};
    float s = ((v[0] + v[1]) + (v[2] + v[3])) + ((v[4] + v[5]) + (v[6] + v[7]));
#pragma unroll
    for (int off = 32; off > 0; off >>= 1) s += __shfl_xor(s, off, 64);
    float mean = s * (1.0f / EMB);
    float s2 = 0.f;
#pragma unroll
    for (int j = 0; j < 8; ++j) { v[j] -= mean; s2 += v[j] * v[j]; }
#pragma unroll
    for (int off = 32; off > 0; off >>= 1) s2 += __shfl_xor(s2, off, 64);
    float rs = rsqrtf(s2 * (1.0f / EMB) + 1e-5f);
    float g[8];
    if (*flag) {
        const ushort_t* wb = (const ushort_t*)w + woff + lane * 8;
        ushort_t tmp[8];
        *(uint4*)tmp = *(const uint4*)wb;
#pragma unroll
        for (int j = 0; j < 8; ++j) g[j] = bf2f(tmp[j]);
    } else {
        const float* wf = (const float*)w + woff + lane * 8;
        float4 g0 = *(const float4*)wf;
        float4 g1 = *(const float4*)(wf + 4);
        g[0] = g0.x; g[1] = g0.y; g[2] = g0.z; g[3] = g0.w;
        g[4] = g1.x; g[5] = g1.y; g[6] = g1.z; g[7] = g1.w;
    }
    ushort_t ob[8];
#pragma unroll
    for (int j = 0; j < 8; ++j) ob[j] = f2bf(v[j] * rs * g[j]);
    *(uint4*)(out + (size_t)row * EMB + lane * 8) = *(uint4*)ob;
}

// ---------------- weight transpose v3: [K,N] dtype -> bf16 [N,K] ---------------
__global__ __launch_bounds__(256) void wtrans_k(const void* __restrict__ aw,
        const void* __restrict__ pw, const void* __restrict__ fw,
        const void* __restrict__ fpw, long l, ushort_t* __restrict__ wbuf,
        const int* __restrict__ flag)
{
    __shared__ float tile[64][65];
    const int isbf = *flag;
    long lay = (l < 0) ? (long)blockIdx.z : l;
    ushort_t* obase = wbuf + ((l < 0) ? (size_t)blockIdx.z * 3145728 : 0);
    int t = blockIdx.x;
    const void* src; ushort_t* dst; int Kw, Nw; long ioff;
    if (t < 192)      { src = aw;  dst = obase;           Kw = 512;  Nw = 1536; ioff = lay * 512L * 1536; }
    else if (t < 256) { t -= 192; src = pw;  dst = obase + 786432;  Kw = 512;  Nw = 512;  ioff = lay * 512L * 512; }
    else if (t < 512) { t -= 256; src = fw;  dst = obase + 1048576; Kw = 512;  Nw = 2048; ioff = lay * 512L * 2048; }
    else              { t -= 512; src = fpw; dst = obase + 2097152; Kw = 2048; Nw = 512;  ioff = lay * 2048L * 512; }
    int tn = Nw >> 6;
    int n0 = (t % tn) * 64, k0 = (t / tn) * 64;
    const int r = threadIdx.x >> 2, cq = (threadIdx.x & 3) * 16;
    size_t ii = ioff + (size_t)(k0 + r) * Nw + n0 + cq;
    if (isbf) {
        const ushort_t* sb = (const ushort_t*)src + ii;
        ushort_t tmp[16];
        *(uint4*)tmp = *(const uint4*)sb;
        *(uint4*)(tmp + 8) = *(const uint4*)(sb + 8);
#pragma unroll
        for (int j = 0; j < 16; ++j) tile[r][cq + j] = bf2f(tmp[j]);
    } else {
        const float* sf = (const float*)src + ii;
        *(float4*)&tile[r][cq]      = *(const float4*)sf;
        *(float4*)&tile[r][cq + 4]  = *(const float4*)(sf + 4);
        *(float4*)&tile[r][cq + 8]  = *(const float4*)(sf + 8);
        *(float4*)&tile[r][cq + 12] = *(const float4*)(sf + 12);
    }
    __syncthreads();
    const int kc = (threadIdx.x & 7) * 8;
#pragma unroll
    for (int j = 0; j < 2; ++j) {
        const int n = (threadIdx.x >> 3) + j * 32;
        unsigned pk[4];
#pragma unroll
        for (int i = 0; i < 4; ++i) {
            unsigned lo = f2bf(tile[kc + 2 * i][n]);
            unsigned hi = f2bf(tile[kc + 2 * i + 1][n]);
            pk[i] = lo | (hi << 16);
        }
        *(uint4*)(dst + (size_t)(n0 + n) * Kw + k0 + kc) = *(uint4*)pk;
    }
}

// ---------------- wte convert (zero-padded to VPAD rows) -----------------------
__global__ __launch_bounds__(256) void wconv_k(const void* __restrict__ in,
        ushort_t* __restrict__ out, int n, int nreal, const int* __restrict__ flag)
{
    int i = blockIdx.x * 256 + threadIdx.x;
    if (i >= n) return;
    ushort_t v = 0;
    if (i < nreal) v = (*flag) ? ((const ushort_t*)in)[i] : f2bf(((const float*)in)[i]);
    out[i] = v;
}

// ---------------- 2-phase static-dbuf NT GEMM: BMx64, BK=64, global_load_lds ---
// MI = m-fragments per wave (BM = MI*64). Distinct __shared__ objects per
// phase (compiler can prove STAGE(odd buf) doesn't alias ds_reads(even buf),
// so NO implicit vmcnt drain lands before the MFMAs). k-loop unrolled x2 with
// compile-time phase; one inline-asm vmcnt(0) + s_barrier per k-step after
// the MFMAs. nk = K/64 is even for all shapes used (K = 512 or 2048).
template<int MI>
__global__ __launch_bounds__(256) void gemm_gl(const ushort_t* __restrict__ A,
        const ushort_t* __restrict__ Bt, int M, int N, int K,
        float* __restrict__ outF, ushort_t* __restrict__ outB, void* __restrict__ outD,
        const float* __restrict__ res, int act, const int* __restrict__ flag)
{
    constexpr int BM = MI * 64;
    __shared__ __align__(16) ushort_t Al0[BM * 64];
    __shared__ __align__(16) ushort_t Al1[BM * 64];
    __shared__ __align__(16) ushort_t Bl0[64 * 64];
    __shared__ __align__(16) ushort_t Bl1[64 * 64];
    const int tid = threadIdx.x;
    const int wave = tid >> 6, lane = tid & 63;
    const int quad = lane >> 4, l16 = lane & 15;
    const int m0 = blockIdx.y * BM, n0 = blockIdx.x * 64;
    const size_t K8 = (size_t)K * 8;           // 8 rows of K in ushorts
    const int sr = lane >> 3, sc = (lane & 7) * 8;
    const ushort_t* Ag = A + (size_t)(m0 + wave * (MI * 16) + sr) * K + sc;
    const ushort_t* Bg = Bt + (size_t)(n0 + wave * 16 + sr) * K + sc;
    const int awoff = (wave * (MI * 16)) * 64;
    const int bwoff = (wave * 16) * 64;
    f32x4 acc[MI][4] = {};

#define STAGE_GL(AL, BL, kt) do { \
        const int k0_ = (kt) << 6; \
        _Pragma("unroll") \
        for (int i = 0; i < MI * 2; ++i) \
            GLOAD16(Ag + k0_ + (size_t)i * K8, &(AL)[awoff + i * 512]); \
        _Pragma("unroll") \
        for (int i = 0; i < 2; ++i) \
            GLOAD16(Bg + k0_ + (size_t)i * K8, &(BL)[bwoff + i * 512]); \
    } while (0)

#define COMPUTE_GL(AL, BL) do { \
        _Pragma("unroll") \
        for (int ks = 0; ks < 2; ++ks) { \
            short8 af[MI], bfr[4]; \
            _Pragma("unroll") \
            for (int mi = 0; mi < MI; ++mi) \
                af[mi] = *(const short8*)&(AL)[(wave * (MI * 16) + mi * 16 + l16) * 64 + ks * 32 + quad * 8]; \
            _Pragma("unroll") \
            for (int ni = 0; ni < 4; ++ni) \
                bfr[ni] = *(const short8*)&(BL)[(ni * 16 + l16) * 64 + ks * 32 + quad * 8]; \
            _Pragma("unroll") \
            for (int mi = 0; mi < MI; ++mi) \
                _Pragma("unroll") \
                for (int ni = 0; ni < 4; ++ni) \
                    acc[mi][ni] = __builtin_amdgcn_mfma_f32_16x16x32_bf16( \
                            af[mi], bfr[ni], acc[mi][ni], 0, 0, 0); \
        } \
    } while (0)

#define KSTEP_SYNC() do { \
        asm volatile("s_waitcnt vmcnt(0)" ::: "memory"); \
        __builtin_amdgcn_s_barrier(); \
    } while (0)

    const int nk = K >> 6;                       // even (8 or 32)
    STAGE_GL(Al0, Bl0, 0);
    KSTEP_SYNC();
    for (int t = 0; t < nk - 2; t += 2) {
        STAGE_GL(Al1, Bl1, t + 1);               // async into odd buffers
        COMPUTE_GL(Al0, Bl0);                    // overlaps in-flight loads
        KSTEP_SYNC();
        STAGE_GL(Al0, Bl0, t + 2);               // async into even buffers
        COMPUTE_GL(Al1, Bl1);
        KSTEP_SYNC();
    }
    STAGE_GL(Al1, Bl1, nk - 1);
    COMPUTE_GL(Al0, Bl0);
    KSTEP_SYNC();
    COMPUTE_GL(Al1, Bl1);
#undef STAGE_GL
#undef COMPUTE_GL
#undef KSTEP_SYNC

    const int isbf = *flag;
#pragma unroll
    for (int mi = 0; mi < MI; ++mi) {
        const int rowb = m0 + wave * (MI * 16) + mi * 16 + quad * 4;
#pragma unroll
        for (int ni = 0; ni < 4; ++ni) {
            const int nn = n0 + ni * 16 + l16;
            if (nn >= N) continue;
#pragma unroll
            for (int r = 0; r < 4; ++r) {
                size_t o = (size_t)(rowb + r) * N + nn;
                float v = acc[mi][ni][r];
                if (res) v += res[o];
                if (act) v = 0.5f * v * (1.0f + erff(v * 0.70710678118f));
                if (outF)      outF[o] = v;
                else if (outB) outB[o] = f2bf(v);
                else if (isbf) ((ushort_t*)outD)[o] = f2bf(v);
                else           ((float*)outD)[o] = v;
            }
        }
    }
}

// ---------------- legacy GEMM (fallback) ---------------------------------------
__global__ __launch_bounds__(256) void gemm_k(const ushort_t* __restrict__ A,
        const void* __restrict__ B, long boff, int M, int N, int K, int bt,
        float* __restrict__ outF, ushort_t* __restrict__ outB, void* __restrict__ outD,
        const float* __restrict__ res, int act, const int* __restrict__ flag)
{
    __shared__ ushort_t Al[64 * 40];
    __shared__ ushort_t Bl[64 * 40];
    const int isbf = *flag;
    const int tid = threadIdx.x;
    const int wave = tid >> 6, lane = tid & 63;
    const int quad = lane >> 4, l16 = lane & 15;
    const int m0 = blockIdx.y * 64, n0 = blockIdx.x * 64;
    const int sr = tid >> 2, sc = (tid & 3) * 8;
    const int kr = tid >> 3, nc = (tid & 7) * 8;
    f32x4 acc[4] = {};
    const bool bok = (n0 + sr) < N;
    const ushort_t* Ag = A + (size_t)(m0 + sr) * K + sc;
    const ushort_t* Bb = (const ushort_t*)B + boff;
    const float*    Bf = (const float*)B + boff;
    const size_t i1 = (size_t)(n0 + sr) * K + sc;
    const size_t i0 = (size_t)kr * N + n0 + nc;
    for (int k0 = 0; k0 < K; k0 += 32) {
        uint4 av = *(const uint4*)(Ag + k0);
        ushort_t b8[8] = {0, 0, 0, 0, 0, 0, 0, 0};
        size_t bi = bt ? (i1 + k0) : (i0 + (size_t)k0 * N);
        if (!bt || bok) {
            if (isbf) *(uint4*)b8 = *(const uint4*)(Bb + bi);
            else {
                float4 f0 = *(const float4*)(Bf + bi);
                float4 f1 = *(const float4*)(Bf + bi + 4);
                b8[0] = f2bf(f0.x); b8[1] = f2bf(f0.y); b8[2] = f2bf(f0.z); b8[3] = f2bf(f0.w);
                b8[4] = f2bf(f1.x); b8[5] = f2bf(f1.y); b8[6] = f2bf(f1.z); b8[7] = f2bf(f1.w);
            }
        }
        __syncthreads();
        *(uint4*)&Al[sr * 40 + sc] = av;
        if (bt) *(uint4*)&Bl[sr * 40 + sc] = *(uint4*)b8;
        else {
#pragma unroll
            for (int i = 0; i < 8; ++i) Bl[(nc + i) * 40 + kr] = b8[i];
        }
        __syncthreads();
        short8 af = *(const short8*)&Al[(wave * 16 + l16) * 40 + quad * 8];
#pragma unroll
        for (int nt = 0; nt < 4; ++nt) {
            short8 bf = *(const short8*)&Bl[(nt * 16 + l16) * 40 + quad * 8];
            acc[nt] = __builtin_amdgcn_mfma_f32_16x16x32_bf16(af, bf, acc[nt], 0, 0, 0);
        }
    }
    const int mb = m0 + wave * 16 + quad * 4;
#pragma unroll
    for (int nt = 0; nt < 4; ++nt) {
        int nn = n0 + nt * 16 + l16;
        if (nn >= N) continue;
#pragma unroll
        for (int r = 0; r < 4; ++r) {
            size_t o = (size_t)(mb + r) * N + nn;
            float v = acc[nt][r];
            if (res) v += res[o];
            if (act) v = 0.5f * v * (1.0f + erff(v * 0.70710678118f));
            if (outF)      outF[o] = v;
            else if (outB) outB[o] = f2bf(v);
            else if (isbf) ((ushort_t*)outD)[o] = f2bf(v);
            else           ((float*)outD)[o] = v;
        }
    }
}

// ---------------- flash attention v4 (causal), 64-key tiles --------------------
__global__ __launch_bounds__(256) void attn_k(const ushort_t* __restrict__ qkv,
        ushort_t* __restrict__ y)
{
    __shared__ ushort_t Kl[64 * 72];
    __shared__ ushort_t Vt[64 * 72];
    __shared__ ushort_t Pl[4][16 * 72];
    const int tid = threadIdx.x, wave = tid >> 6, lane = tid & 63;
    const int quad = lane >> 4, l16 = lane & 15;
    const int qt = (int)gridDim.x - 1 - blockIdx.x;
    const int b = blockIdx.y >> 3, h = blockIdx.y & 7;
    const int q0b = qt * 64;
    const int q0w = q0b + wave * 16;
    const size_t rstr = 3 * EMB;
    const ushort_t* qbase = qkv + ((size_t)(b * TS) + q0w + l16) * rstr + h * 64;
    short8 qf0, qf1;
    {   // load Q and pre-scale by 1/8 (exact in bf16)
        ushort_t q0[8], q1[8];
        *(uint4*)q0 = *(const uint4*)(qbase + quad * 8);
        *(uint4*)q1 = *(const uint4*)(qbase + 32 + quad * 8);
#pragma unroll
        for (int i = 0; i < 8; ++i) {
            qf0[i] = (short)f2bf(bf2f(q0[i]) * 0.125f);
            qf1[i] = (short)f2bf(bf2f(q1[i]) * 0.125f);
        }
    }
    short8 onesf;
#pragma unroll
    for (int i = 0; i < 8; ++i) onesf[i] = (short)0x3F80;   // bf16 1.0
    f32x4 O[4] = {};
    f32x4 lacc = {};
    const int sk = tid >> 2, sdc = (tid & 3) * 16;
    const int vp = tid >> 3, vdc = (tid & 7) * 8;
    const int vsh = 16 * ((tid & 7) & 3);
    const int vcol = (2 * vp + vsh) & 63;
    for (int kt = 0; kt <= qt; ++kt) {
        const int k0 = kt * 64;
        const ushort_t* krow = qkv + ((size_t)(b * TS) + k0 + sk) * rstr + EMB + h * 64 + sdc;
        uint4 kv0 = *(const uint4*)krow;
        uint4 kv1 = *(const uint4*)(krow + 8);
        const ushort_t* vrow = qkv + ((size_t)(b * TS) + k0 + 2 * vp) * rstr + 2 * EMB + h * 64 + vdc;
        uint4 vv0 = *(const uint4*)vrow;
        uint4 vv1 = *(const uint4*)(vrow + rstr);
        __syncthreads();
        *(uint4*)&Kl[sk * 72 + sdc]     = kv0;
        *(uint4*)&Kl[sk * 72 + sdc + 8] = kv1;
        {
            ushort_t v0[8], v1[8];
            *(uint4*)v0 = vv0; *(uint4*)v1 = vv1;
#pragma unroll
            for (int i = 0; i < 8; ++i) {
                unsigned pk = (unsigned)v0[i] | ((unsigned)v1[i] << 16);
                *(unsigned*)&Vt[(vdc + i) * 72 + vcol] = pk;
            }
        }
        __syncthreads();
        if (kt < qt) {                                 // bulk tile: no masking
            f32x4 S[4] = {};
#pragma unroll
            for (int nt = 0; nt < 4; ++nt) {
                short8 kf0 = *(const short8*)&Kl[(nt * 16 + l16) * 72 + quad * 8];
                short8 kf1 = *(const short8*)&Kl[(nt * 16 + l16) * 72 + 32 + quad * 8];
                S[nt] = __builtin_amdgcn_mfma_f32_16x16x32_bf16(qf0, kf0, S[nt], 0, 0, 0);
                S[nt] = __builtin_amdgcn_mfma_f32_16x16x32_bf16(qf1, kf1, S[nt], 0, 0, 0);
            }
#pragma unroll
            for (int nt = 0; nt < 4; ++nt)
#pragma unroll
                for (int r = 0; r < 4; ++r)
                    Pl[wave][(quad * 4 + r) * 72 + nt * 16 + l16] = f2bf(__expf(S[nt][r]));
        } else {                                       // diagonal tile: masked
            f32x4 S[4] = {};
#pragma unroll
            for (int nt = 0; nt < 4; ++nt) {
                if (nt > wave) continue;
                short8 kf0 = *(const short8*)&Kl[(nt * 16 + l16) * 72 + quad * 8];
                short8 kf1 = *(const short8*)&Kl[(nt * 16 + l16) * 72 + 32 + quad * 8];
                S[nt] = __builtin_amdgcn_mfma_f32_16x16x32_bf16(qf0, kf0, S[nt], 0, 0, 0);
                S[nt] = __builtin_amdgcn_mfma_f32_16x16x32_bf16(qf1, kf1, S[nt], 0, 0, 0);
            }
#pragma unroll
            for (int nt = 0; nt < 4; ++nt)
#pragma unroll
                for (int r = 0; r < 4; ++r) {
                    bool live = (nt < wave) || (nt == wave && l16 <= quad * 4 + r);
                    float p = live ? __expf(S[nt][r]) : 0.f;
                    Pl[wave][(quad * 4 + r) * 72 + nt * 16 + l16] = f2bf(p);
                }
        }
#pragma unroll
        for (int kc = 0; kc < 2; ++kc) {
            short8 pf = *(const short8*)&Pl[wave][l16 * 72 + kc * 32 + quad * 8];
            lacc = __builtin_amdgcn_mfma_f32_16x16x32_bf16(pf, onesf, lacc, 0, 0, 0);
#pragma unroll
            for (int dt = 0; dt < 4; ++dt) {
                int d = dt * 16 + l16;
                int sh = ((2 * dt + (l16 >> 3)) & 3) * 16;
                int col = (kc * 32 + quad * 8 + sh) & 63;
                short8 vf = *(const short8*)&Vt[d * 72 + col];
                O[dt] = __builtin_amdgcn_mfma_f32_16x16x32_bf16(pf, vf, O[dt], 0, 0, 0);
            }
        }
    }
#pragma unroll
    for (int dt = 0; dt < 4; ++dt)
#pragma unroll
        for (int r = 0; r < 4; ++r) {
            int q = q0w + quad * 4 + r;
            float v = O[dt][r] / lacc[r];
            y[((size_t)(b * TS) + q) * EMB + h * 64 + dt * 16 + l16] = f2bf(v);
        }
}

// ---------------- host ---------------------------------------------------------
extern "C" void kernel_launch(void* const* d_in, const int* in_sizes, int n_in,
                              void* d_out, int out_size, void* d_ws, size_t ws_size,
                              hipStream_t stream)
{
    const int*  idx    = (const int*)d_in[0];
    const void* wte    = d_in[1];
    const void* wpe    = d_in[2];
    const void* attn_w = d_in[3];   // [L,512,1536]
    const void* proj_w = d_in[4];   // [L,512,512]
    const void* fc_w   = d_in[5];   // [L,512,2048]
    const void* fcp_w  = d_in[6];   // [L,2048,512]
    const void* ln1_w  = d_in[7];
    const void* ln2_w  = d_in[8];
    const void* lnf_w  = d_in[9];

    const size_t sz_xw    = (size_t)NTOK * EMB * 4;
    const size_t sz_hbf   = (size_t)NTOK * EMB * 2;
    const size_t sz_big   = (size_t)NTOK * 2048 * 2;
    const size_t sz_wteb  = (size_t)VPAD * EMB * 2;
    const size_t sz_wbuf1 = (size_t)3145728 * 2;
    const size_t need_legacy = 256 + sz_xw + sz_hbf + sz_big;
    const size_t need_fast   = need_legacy + sz_wteb + sz_wbuf1;
    const size_t need_all    = need_legacy + sz_wteb + NL * sz_wbuf1;   // ~80 MB

    if (ws_size < need_legacy) {
        sentinel_k<<<(out_size + 255) / 256, 256, 0, stream>>>((ushort_t*)d_out, out_size);
        return;
    }
    int* flag = (int*)d_ws;
    char* p = (char*)d_ws + 256;
    float*    xw  = (float*)p;    p += sz_xw;
    ushort_t* hbf = (ushort_t*)p; p += sz_hbf;
    ushort_t* big = (ushort_t*)p; p += sz_big;

    detect_k<<<1, 64, 0, stream>>>((const ushort_t*)wte, flag);
    embed_k<<<NTOK, 256, 0, stream>>>(idx, wte, wpe, xw, flag);

    if (ws_size >= need_fast) {
        ushort_t* wteb = (ushort_t*)p; p += sz_wteb;
        ushort_t* wbuf = (ushort_t*)p;
        const bool allw = (ws_size >= need_all);
        wconv_k<<<(VPAD * EMB + 255) / 256, 256, 0, stream>>>(wte, wteb,
                VPAD * EMB, VOCAB * EMB, flag);
        if (allw)
            wtrans_k<<<dim3(768, 1, NL), 256, 0, stream>>>(attn_w, proj_w, fc_w, fcp_w,
                    -1, wbuf, flag);
        for (int l = 0; l < NL; ++l) {
            ushort_t* wb = allw ? (wbuf + (size_t)l * 3145728) : wbuf;
            if (!allw)
                wtrans_k<<<dim3(768, 1, 1), 256, 0, stream>>>(attn_w, proj_w, fc_w, fcp_w,
                        (long)l, wbuf, flag);
            ln_k<<<NTOK / 4, 256, 0, stream>>>(xw, ln1_w, (long)l * EMB, hbf, flag);
            gemm_gl<2><<<dim3(24, 32), 256, 0, stream>>>(hbf, wb,
                    NTOK, 1536, 512, nullptr, big, nullptr, nullptr, 0, flag);
            attn_k<<<dim3(16, 32), 256, 0, stream>>>(big, hbf);
            gemm_gl<1><<<dim3(8, 64), 256, 0, stream>>>(hbf, wb + 786432,
                    NTOK, 512, 512, xw, nullptr, nullptr, xw, 0, flag);
            ln_k<<<NTOK / 4, 256, 0, stream>>>(xw, ln2_w, (long)l * EMB, hbf, flag);
            gemm_gl<2><<<dim3(32, 32), 256, 0, stream>>>(hbf, wb + 1048576,
                    NTOK, 2048, 512, nullptr, big, nullptr, nullptr, 1 /*gelu*/, flag);
            gemm_gl<1><<<dim3(8, 64), 256, 0, stream>>>(big, wb + 2097152,
                    NTOK, 512, 2048, xw, nullptr, nullptr, xw, 0, flag);
        }
        ln_k<<<NTOK / 4, 256, 0, stream>>>(xw, lnf_w, 0, hbf, flag);
        gemm_gl<1><<<dim3(6, 64), 256, 0, stream>>>(hbf, wteb,
                NTOK, VOCAB, 512, nullptr, nullptr, d_out, nullptr, 0, flag);
    } else {
        for (int l = 0; l < NL; ++l) {
            ln_k<<<NTOK / 4, 256, 0, stream>>>(xw, ln1_w, (long)l * EMB, hbf, flag);
            gemm_k<<<dim3(24, 64), 256, 0, stream>>>(hbf, attn_w, (long)l * 512 * 1536,
                    NTOK, 1536, 512, 0, nullptr, big, nullptr, nullptr, 0, flag);
            attn_k<<<dim3(16, 32), 256, 0, stream>>>(big, hbf);
            gemm_k<<<dim3(8, 64), 256, 0, stream>>>(hbf, proj_w, (long)l * 512 * 512,
                    NTOK, 512, 512, 0, xw, nullptr, nullptr, xw, 0, flag);
            ln_k<<<NTOK / 4, 256, 0, stream>>>(xw, ln2_w, (long)l * EMB, hbf, flag);
            gemm_k<<<dim3(32, 64), 256, 0, stream>>>(hbf, fc_w, (long)l * 512 * 2048,
                    NTOK, 2048, 512, 0, nullptr, big, nullptr, nullptr, 1, flag);
            gemm_k<<<dim3(8, 64), 256, 0, stream>>>(big, fcp_w, (long)l * 2048 * 512,
                    NTOK, 512, 2048, 0, xw, nullptr, nullptr, xw, 0, flag);
        }
        ln_k<<<NTOK / 4, 256, 0, stream>>>(xw, lnf_w, 0, hbf, flag);
        gemm_k<<<dim3(6, 64), 256, 0, stream>>>(hbf, wte, 0,
                NTOK, VOCAB, 512, 1, nullptr, nullptr, d_out, nullptr, 0, flag);
    }
}

// Round 4
// 1108.862 us; speedup vs baseline: 1.1494x; 1.0501x over previous
//
#include <hip/hip_runtime.h>

// GPT forward, MI355X gfx950.
// Shapes: V=371 E=512 H=8 L=8 B=4 T=1024 D=64, N=B*T=4096.
// Inputs float32 (runtime-detected, bf16 supported); output matches input fmt.
// r13: revert to r9's reg-staged GEMM/attn structures (beat all gl-variants),
// + T14 issue-early/write-late prefetch: next tile's global loads issue AFTER
// the LDS-write barrier (fly during MFMA phase, consumed at next iteration's
// LDS write). Applied to gemm_wide, gemm_nt, attn_k. wtrans/ln unchanged.

#define VOCAB 371
#define VPAD  384
#define EMB   512
#define NH    8
#define NL    8
#define TS    1024
#define NTOK  4096
#define NEG_INF (-1e30f)

typedef unsigned short ushort_t;
typedef __attribute__((ext_vector_type(8))) short short8;
typedef __attribute__((ext_vector_type(4))) float f32x4;

__device__ inline float bf2f(ushort_t b) {
    unsigned int u = ((unsigned int)b) << 16;
    float f; __builtin_memcpy(&f, &u, 4); return f;
}
__device__ inline ushort_t f2bf(float f) {
    unsigned int u; __builtin_memcpy(&u, &f, 4);
    u = (u + 0x7fff + ((u >> 16) & 1)) >> 16;   // RNE
    return (ushort_t)u;
}

// ---------------- dtype probe ---------------------------------------------------
__global__ __launch_bounds__(64) void detect_k(const ushort_t* __restrict__ w,
        int* __restrict__ flag)
{
    int i = threadIdx.x;
    float v = bf2f(w[2 * i]);
    bool ok = (__builtin_fabsf(v) <= 4.0f);
    unsigned long long m = __ballot(ok);
    if (i == 0) flag[0] = (__popcll(m) >= 56) ? 1 : 0;   // 1 = bf16, 0 = float32
}

// ---------------- ws-too-small sentinel ----------------------------------------
__global__ __launch_bounds__(256) void sentinel_k(ushort_t* __restrict__ out, int n)
{
    int i = blockIdx.x * 256 + threadIdx.x;
    if (i < n) out[i] = 0x447A;
}

// ---------------- embedding ----------------------------------------------------
__global__ __launch_bounds__(256) void embed_k(const int* __restrict__ idx,
        const void* __restrict__ wte, const void* __restrict__ wpe,
        float* __restrict__ x, const int* __restrict__ flag)
{
    int n = blockIdx.x, tid = threadIdx.x;
    int t = n & (TS - 1);
    int v = idx[n];
    size_t o = (size_t)n * EMB;
    float a0, a1, b0, b1;
    if (*flag) {
        const ushort_t* te = (const ushort_t*)wte; const ushort_t* pe = (const ushort_t*)wpe;
        a0 = bf2f(te[v * EMB + tid]); a1 = bf2f(te[v * EMB + 256 + tid]);
        b0 = bf2f(pe[t * EMB + tid]); b1 = bf2f(pe[t * EMB + 256 + tid]);
    } else {
        const float* te = (const float*)wte; const float* pe = (const float*)wpe;
        a0 = te[v * EMB + tid]; a1 = te[v * EMB + 256 + tid];
        b0 = pe[t * EMB + tid]; b1 = pe[t * EMB + 256 + tid];
    }
    x[o + tid] = a0 + b0;
    x[o + 256 + tid] = a1 + b1;
}

// ---------------- layernorm v2: one wave per row, no barriers ------------------
__global__ __launch_bounds__(256) void ln_k(const float* __restrict__ x,
        const void* __restrict__ w, long woff, ushort_t* __restrict__ out,
        const int* __restrict__ flag)
{
    const int row = blockIdx.x * 4 + (threadIdx.x >> 6);
    const int lane = threadIdx.x & 63;
    const float* xr = x + (size_t)row * EMB + lane * 8;
    float4 f0 = *(const float4*)xr;
    float4 f1 = *(const float4*)(xr + 4);
    float v[8] = {f0.x, f0.y, f0.z, f0.w, f1.x, f1.y, f1.z, f1.w};
    float s = ((v[0] + v[1]) + (v[2] + v[3])) + ((v[4] + v[5]) + (v[6] + v[7]));
#pragma unroll
    for (int off = 32; off > 0; off >>= 1) s += __shfl_xor(s, off, 64);
    float mean = s * (1.0f / EMB);
    float s2 = 0.f;
#pragma unroll
    for (int j = 0; j < 8; ++j) { v[j] -= mean; s2 += v[j] * v[j]; }
#pragma unroll
    for (int off = 32; off > 0; off >>= 1) s2 += __shfl_xor(s2, off, 64);
    float rs = rsqrtf(s2 * (1.0f / EMB) + 1e-5f);
    float g[8];
    if (*flag) {
        const ushort_t* wb = (const ushort_t*)w + woff + lane * 8;
        ushort_t tmp[8];
        *(uint4*)tmp = *(const uint4*)wb;
#pragma unroll
        for (int j = 0; j < 8; ++j) g[j] = bf2f(tmp[j]);
    } else {
        const float* wf = (const float*)w + woff + lane * 8;
        float4 g0 = *(const float4*)wf;
        float4 g1 = *(const float4*)(wf + 4);
        g[0] = g0.x; g[1] = g0.y; g[2] = g0.z; g[3] = g0.w;
        g[4] = g1.x; g[5] = g1.y; g[6] = g1.z; g[7] = g1.w;
    }
    ushort_t ob[8];
#pragma unroll
    for (int j = 0; j < 8; ++j) ob[j] = f2bf(v[j] * rs * g[j]);
    *(uint4*)(out + (size_t)row * EMB + lane * 8) = *(uint4*)ob;
}

// ---------------- weight transpose v3: [K,N] dtype -> bf16 [N,K] ---------------
__global__ __launch_bounds__(256) void wtrans_k(const void* __restrict__ aw,
        const void* __restrict__ pw, const void* __restrict__ fw,
        const void* __restrict__ fpw, long l, ushort_t* __restrict__ wbuf,
        const int* __restrict__ flag)
{
    __shared__ float tile[64][65];
    const int isbf = *flag;
    long lay = (l < 0) ? (long)blockIdx.z : l;
    ushort_t* obase = wbuf + ((l < 0) ? (size_t)blockIdx.z * 3145728 : 0);
    int t = blockIdx.x;
    const void* src; ushort_t* dst; int Kw, Nw; long ioff;
    if (t < 192)      { src = aw;  dst = obase;           Kw = 512;  Nw = 1536; ioff = lay * 512L * 1536; }
    else if (t < 256) { t -= 192; src = pw;  dst = obase + 786432;  Kw = 512;  Nw = 512;  ioff = lay * 512L * 512; }
    else if (t < 512) { t -= 256; src = fw;  dst = obase + 1048576; Kw = 512;  Nw = 2048; ioff = lay * 512L * 2048; }
    else              { t -= 512; src = fpw; dst = obase + 2097152; Kw = 2048; Nw = 512;  ioff = lay * 2048L * 512; }
    int tn = Nw >> 6;
    int n0 = (t % tn) * 64, k0 = (t / tn) * 64;
    const int r = threadIdx.x >> 2, cq = (threadIdx.x & 3) * 16;
    size_t ii = ioff + (size_t)(k0 + r) * Nw + n0 + cq;
    if (isbf) {
        const ushort_t* sb = (const ushort_t*)src + ii;
        ushort_t tmp[16];
        *(uint4*)tmp = *(const uint4*)sb;
        *(uint4*)(tmp + 8) = *(const uint4*)(sb + 8);
#pragma unroll
        for (int j = 0; j < 16; ++j) tile[r][cq + j] = bf2f(tmp[j]);
    } else {
        const float* sf = (const float*)src + ii;
        *(float4*)&tile[r][cq]      = *(const float4*)sf;
        *(float4*)&tile[r][cq + 4]  = *(const float4*)(sf + 4);
        *(float4*)&tile[r][cq + 8]  = *(const float4*)(sf + 8);
        *(float4*)&tile[r][cq + 12] = *(const float4*)(sf + 12);
    }
    __syncthreads();
    const int kc = (threadIdx.x & 7) * 8;
#pragma unroll
    for (int j = 0; j < 2; ++j) {
        const int n = (threadIdx.x >> 3) + j * 32;
        unsigned pk[4];
#pragma unroll
        for (int i = 0; i < 4; ++i) {
            unsigned lo = f2bf(tile[kc + 2 * i][n]);
            unsigned hi = f2bf(tile[kc + 2 * i + 1][n]);
            pk[i] = lo | (hi << 16);
        }
        *(uint4*)(dst + (size_t)(n0 + n) * Kw + k0 + kc) = *(uint4*)pk;
    }
}

// ---------------- wte convert (zero-padded to VPAD rows) -----------------------
__global__ __launch_bounds__(256) void wconv_k(const void* __restrict__ in,
        ushort_t* __restrict__ out, int n, int nreal, const int* __restrict__ flag)
{
    int i = blockIdx.x * 256 + threadIdx.x;
    if (i >= n) return;
    ushort_t v = 0;
    if (i < nreal) v = (*flag) ? ((const ushort_t*)in)[i] : f2bf(((const float*)in)[i]);
    out[i] = v;
}

// ---------------- wide NT GEMM: 128x64 tile, BK=64 + T14 prefetch --------------
// r9 structure; loads for tile k+1 issue AFTER the LDS-write barrier so they
// overlap the MFMA phase, consumed at next iteration's LDS write.
__global__ __launch_bounds__(256) void gemm_wide(const ushort_t* __restrict__ A,
        const ushort_t* __restrict__ Bt, int M, int N, int K,
        float* __restrict__ outF, ushort_t* __restrict__ outB,
        const float* __restrict__ res, int act)
{
    __shared__ ushort_t Al[128 * 72];
    __shared__ ushort_t Bl[64 * 72];
    const int tid = threadIdx.x;
    const int wave = tid >> 6, lane = tid & 63;
    const int quad = lane >> 4, l16 = lane & 15;
    const int m0 = blockIdx.y * 128, n0 = blockIdx.x * 64;
    const int ar = tid >> 1, ac = (tid & 1) * 32;
    const int br = tid >> 2, bc = (tid & 3) * 16;
    const ushort_t* Ag = A + (size_t)(m0 + ar) * K + ac;
    const ushort_t* Bg = Bt + (size_t)(n0 + br) * K + bc;
    f32x4 acc[2][4] = {};
    uint4 a0 = *(const uint4*)(Ag);
    uint4 a1 = *(const uint4*)(Ag + 8);
    uint4 a2 = *(const uint4*)(Ag + 16);
    uint4 a3 = *(const uint4*)(Ag + 24);
    uint4 b0 = *(const uint4*)(Bg);
    uint4 b1 = *(const uint4*)(Bg + 8);
    for (int k0 = 0; k0 < K; k0 += 64) {
        __syncthreads();
        *(uint4*)&Al[ar * 72 + ac]      = a0;
        *(uint4*)&Al[ar * 72 + ac + 8]  = a1;
        *(uint4*)&Al[ar * 72 + ac + 16] = a2;
        *(uint4*)&Al[ar * 72 + ac + 24] = a3;
        *(uint4*)&Bl[br * 72 + bc]     = b0;
        *(uint4*)&Bl[br * 72 + bc + 8] = b1;
        __syncthreads();
        if (k0 + 64 < K) {                      // prefetch: flies during MFMAs
            a0 = *(const uint4*)(Ag + k0 + 64);
            a1 = *(const uint4*)(Ag + k0 + 72);
            a2 = *(const uint4*)(Ag + k0 + 80);
            a3 = *(const uint4*)(Ag + k0 + 88);
            b0 = *(const uint4*)(Bg + k0 + 64);
            b1 = *(const uint4*)(Bg + k0 + 72);
        }
#pragma unroll
        for (int ks = 0; ks < 2; ++ks) {
            short8 af[2], bf[4];
#pragma unroll
            for (int mi = 0; mi < 2; ++mi)
                af[mi] = *(const short8*)&Al[(wave * 32 + mi * 16 + l16) * 72 + ks * 32 + quad * 8];
#pragma unroll
            for (int ni = 0; ni < 4; ++ni)
                bf[ni] = *(const short8*)&Bl[(ni * 16 + l16) * 72 + ks * 32 + quad * 8];
#pragma unroll
            for (int mi = 0; mi < 2; ++mi)
#pragma unroll
                for (int ni = 0; ni < 4; ++ni)
                    acc[mi][ni] = __builtin_amdgcn_mfma_f32_16x16x32_bf16(
                            af[mi], bf[ni], acc[mi][ni], 0, 0, 0);
        }
    }
#pragma unroll
    for (int mi = 0; mi < 2; ++mi) {
        const int rowb = m0 + wave * 32 + mi * 16 + quad * 4;
#pragma unroll
        for (int ni = 0; ni < 4; ++ni) {
            const int col = n0 + ni * 16 + l16;
#pragma unroll
            for (int r = 0; r < 4; ++r) {
                size_t o = (size_t)(rowb + r) * N + col;
                float v = acc[mi][ni][r];
                if (res) v += res[o];
                if (act) v = 0.5f * v * (1.0f + erff(v * 0.70710678118f));
                if (outF) outF[o] = v;
                else      outB[o] = f2bf(v);
            }
        }
    }
}

// ---------------- small NT GEMM (proj/fcp/logits) + T14 prefetch ---------------
__global__ __launch_bounds__(256) void gemm_nt(const ushort_t* __restrict__ A,
        const ushort_t* __restrict__ Bt, int M, int N, int K,
        float* __restrict__ outF, ushort_t* __restrict__ outB, void* __restrict__ outD,
        const float* __restrict__ res, int act, const int* __restrict__ flag)
{
    __shared__ ushort_t Al[64 * 72];
    __shared__ ushort_t Bl[64 * 72];
    const int isbf = *flag;
    const int tid = threadIdx.x;
    const int wave = tid >> 6, lane = tid & 63;
    const int quad = lane >> 4, l16 = lane & 15;
    const int m0 = blockIdx.y * 64, n0 = blockIdx.x * 64;
    const int sr = tid >> 2, sc = (tid & 3) * 16;
    const bool bok = (n0 + sr) < N;
    const ushort_t* Ag = A + (size_t)(m0 + sr) * K + sc;
    const ushort_t* Bg = Bt + (size_t)(n0 + sr) * K + sc;
    f32x4 acc[4] = {};
    uint4 a0 = *(const uint4*)(Ag);
    uint4 a1 = *(const uint4*)(Ag + 8);
    uint4 b0 = make_uint4(0, 0, 0, 0), b1 = make_uint4(0, 0, 0, 0);
    if (bok) { b0 = *(const uint4*)(Bg); b1 = *(const uint4*)(Bg + 8); }
    for (int k0 = 0; k0 < K; k0 += 64) {
        __syncthreads();
        *(uint4*)&Al[sr * 72 + sc] = a0; *(uint4*)&Al[sr * 72 + sc + 8] = a1;
        *(uint4*)&Bl[sr * 72 + sc] = b0; *(uint4*)&Bl[sr * 72 + sc + 8] = b1;
        __syncthreads();
        if (k0 + 64 < K) {                      // prefetch: flies during MFMAs
            a0 = *(const uint4*)(Ag + k0 + 64);
            a1 = *(const uint4*)(Ag + k0 + 72);
            if (bok) {
                b0 = *(const uint4*)(Bg + k0 + 64);
                b1 = *(const uint4*)(Bg + k0 + 72);
            }
        }
#pragma unroll
        for (int kc = 0; kc < 2; ++kc) {
            short8 af = *(const short8*)&Al[(wave * 16 + l16) * 72 + kc * 32 + quad * 8];
#pragma unroll
            for (int nt = 0; nt < 4; ++nt) {
                short8 bf = *(const short8*)&Bl[(nt * 16 + l16) * 72 + kc * 32 + quad * 8];
                acc[nt] = __builtin_amdgcn_mfma_f32_16x16x32_bf16(af, bf, acc[nt], 0, 0, 0);
            }
        }
    }
    const int mb = m0 + wave * 16 + quad * 4;
#pragma unroll
    for (int nt = 0; nt < 4; ++nt) {
        int nn = n0 + nt * 16 + l16;
        if (nn >= N) continue;
#pragma unroll
        for (int r = 0; r < 4; ++r) {
            size_t o = (size_t)(mb + r) * N + nn;
            float v = acc[nt][r];
            if (res) v += res[o];
            if (act) v = 0.5f * v * (1.0f + erff(v * 0.70710678118f));
            if (outF)      outF[o] = v;
            else if (outB) outB[o] = f2bf(v);
            else if (isbf) ((ushort_t*)outD)[o] = f2bf(v);
            else           ((float*)outD)[o] = v;
        }
    }
}

// ---------------- legacy GEMM (fallback) ---------------------------------------
__global__ __launch_bounds__(256) void gemm_k(const ushort_t* __restrict__ A,
        const void* __restrict__ B, long boff, int M, int N, int K, int bt,
        float* __restrict__ outF, ushort_t* __restrict__ outB, void* __restrict__ outD,
        const float* __restrict__ res, int act, const int* __restrict__ flag)
{
    __shared__ ushort_t Al[64 * 40];
    __shared__ ushort_t Bl[64 * 40];
    const int isbf = *flag;
    const int tid = threadIdx.x;
    const int wave = tid >> 6, lane = tid & 63;
    const int quad = lane >> 4, l16 = lane & 15;
    const int m0 = blockIdx.y * 64, n0 = blockIdx.x * 64;
    const int sr = tid >> 2, sc = (tid & 3) * 8;
    const int kr = tid >> 3, nc = (tid & 7) * 8;
    f32x4 acc[4] = {};
    const bool bok = (n0 + sr) < N;
    const ushort_t* Ag = A + (size_t)(m0 + sr) * K + sc;
    const ushort_t* Bb = (const ushort_t*)B + boff;
    const float*    Bf = (const float*)B + boff;
    const size_t i1 = (size_t)(n0 + sr) * K + sc;
    const size_t i0 = (size_t)kr * N + n0 + nc;
    for (int k0 = 0; k0 < K; k0 += 32) {
        uint4 av = *(const uint4*)(Ag + k0);
        ushort_t b8[8] = {0, 0, 0, 0, 0, 0, 0, 0};
        size_t bi = bt ? (i1 + k0) : (i0 + (size_t)k0 * N);
        if (!bt || bok) {
            if (isbf) *(uint4*)b8 = *(const uint4*)(Bb + bi);
            else {
                float4 f0 = *(const float4*)(Bf + bi);
                float4 f1 = *(const float4*)(Bf + bi + 4);
                b8[0] = f2bf(f0.x); b8[1] = f2bf(f0.y); b8[2] = f2bf(f0.z); b8[3] = f2bf(f0.w);
                b8[4] = f2bf(f1.x); b8[5] = f2bf(f1.y); b8[6] = f2bf(f1.z); b8[7] = f2bf(f1.w);
            }
        }
        __syncthreads();
        *(uint4*)&Al[sr * 40 + sc] = av;
        if (bt) *(uint4*)&Bl[sr * 40 + sc] = *(uint4*)b8;
        else {
#pragma unroll
            for (int i = 0; i < 8; ++i) Bl[(nc + i) * 40 + kr] = b8[i];
        }
        __syncthreads();
        short8 af = *(const short8*)&Al[(wave * 16 + l16) * 40 + quad * 8];
#pragma unroll
        for (int nt = 0; nt < 4; ++nt) {
            short8 bf = *(const short8*)&Bl[(nt * 16 + l16) * 40 + quad * 8];
            acc[nt] = __builtin_amdgcn_mfma_f32_16x16x32_bf16(af, bf, acc[nt], 0, 0, 0);
        }
    }
    const int mb = m0 + wave * 16 + quad * 4;
#pragma unroll
    for (int nt = 0; nt < 4; ++nt) {
        int nn = n0 + nt * 16 + l16;
        if (nn >= N) continue;
#pragma unroll
        for (int r = 0; r < 4; ++r) {
            size_t o = (size_t)(mb + r) * N + nn;
            float v = acc[nt][r];
            if (res) v += res[o];
            if (act) v = 0.5f * v * (1.0f + erff(v * 0.70710678118f));
            if (outF)      outF[o] = v;
            else if (outB) outB[o] = f2bf(v);
            else if (isbf) ((ushort_t*)outD)[o] = f2bf(v);
            else           ((float*)outD)[o] = v;
        }
    }
}

// ---------------- flash attention v5 (causal), 64-key tiles + T14 prefetch -----
// r9 v4 structure (static softmax m=0, MFMA-ones l-sum) with K/V tile loads
// for kt+1 issued after the LDS-write barrier of kt, so they overlap the
// QK/softmax/PV compute phase.
__global__ __launch_bounds__(256) void attn_k(const ushort_t* __restrict__ qkv,
        ushort_t* __restrict__ y)
{
    __shared__ ushort_t Kl[64 * 72];
    __shared__ ushort_t Vt[64 * 72];
    __shared__ ushort_t Pl[4][16 * 72];
    const int tid = threadIdx.x, wave = tid >> 6, lane = tid & 63;
    const int quad = lane >> 4, l16 = lane & 15;
    const int qt = (int)gridDim.x - 1 - blockIdx.x;
    const int b = blockIdx.y >> 3, h = blockIdx.y & 7;
    const int q0b = qt * 64;
    const int q0w = q0b + wave * 16;
    const size_t rstr = 3 * EMB;
    const ushort_t* qbase = qkv + ((size_t)(b * TS) + q0w + l16) * rstr + h * 64;
    short8 qf0, qf1;
    {   // load Q and pre-scale by 1/8 (exact in bf16)
        ushort_t q0[8], q1[8];
        *(uint4*)q0 = *(const uint4*)(qbase + quad * 8);
        *(uint4*)q1 = *(const uint4*)(qbase + 32 + quad * 8);
#pragma unroll
        for (int i = 0; i < 8; ++i) {
            qf0[i] = (short)f2bf(bf2f(q0[i]) * 0.125f);
            qf1[i] = (short)f2bf(bf2f(q1[i]) * 0.125f);
        }
    }
    short8 onesf;
#pragma unroll
    for (int i = 0; i < 8; ++i) onesf[i] = (short)0x3F80;   // bf16 1.0
    f32x4 O[4] = {};
    f32x4 lacc = {};
    const int sk = tid >> 2, sdc = (tid & 3) * 16;
    const int vp = tid >> 3, vdc = (tid & 7) * 8;
    const int vsh = 16 * ((tid & 7) & 3);
    const int vcol = (2 * vp + vsh) & 63;
    const ushort_t* kbase = qkv + ((size_t)(b * TS) + sk) * rstr + EMB + h * 64 + sdc;
    const ushort_t* vbase = qkv + ((size_t)(b * TS) + 2 * vp) * rstr + 2 * EMB + h * 64 + vdc;
    uint4 kv0 = *(const uint4*)(kbase);
    uint4 kv1 = *(const uint4*)(kbase + 8);
    uint4 vv0 = *(const uint4*)(vbase);
    uint4 vv1 = *(const uint4*)(vbase + rstr);
    for (int kt = 0; kt <= qt; ++kt) {
        __syncthreads();                 // all waves done reading Kl/Vt (prev)
        *(uint4*)&Kl[sk * 72 + sdc]     = kv0;
        *(uint4*)&Kl[sk * 72 + sdc + 8] = kv1;
        {
            ushort_t v0[8], v1[8];
            *(uint4*)v0 = vv0; *(uint4*)v1 = vv1;
#pragma unroll
            for (int i = 0; i < 8; ++i) {
                unsigned pk = (unsigned)v0[i] | ((unsigned)v1[i] << 16);
                *(unsigned*)&Vt[(vdc + i) * 72 + vcol] = pk;
            }
        }
        __syncthreads();                 // tile kt visible
        if (kt < qt) {                   // prefetch kt+1: flies during compute
            const size_t off = (size_t)(kt + 1) * 64 * rstr;
            kv0 = *(const uint4*)(kbase + off);
            kv1 = *(const uint4*)(kbase + off + 8);
            vv0 = *(const uint4*)(vbase + off);
            vv1 = *(const uint4*)(vbase + off + rstr);
        }
        if (kt < qt) {                                 // bulk tile: no masking
            f32x4 S[4] = {};
#pragma unroll
            for (int nt = 0; nt < 4; ++nt) {
                short8 kf0 = *(const short8*)&Kl[(nt * 16 + l16) * 72 + quad * 8];
                short8 kf1 = *(const short8*)&Kl[(nt * 16 + l16) * 72 + 32 + quad * 8];
                S[nt] = __builtin_amdgcn_mfma_f32_16x16x32_bf16(qf0, kf0, S[nt], 0, 0, 0);
                S[nt] = __builtin_amdgcn_mfma_f32_16x16x32_bf16(qf1, kf1, S[nt], 0, 0, 0);
            }
#pragma unroll
            for (int nt = 0; nt < 4; ++nt)
#pragma unroll
                for (int r = 0; r < 4; ++r)
                    Pl[wave][(quad * 4 + r) * 72 + nt * 16 + l16] = f2bf(__expf(S[nt][r]));
        } else {                                       // diagonal tile: masked
            f32x4 S[4] = {};
#pragma unroll
            for (int nt = 0; nt < 4; ++nt) {
                if (nt > wave) continue;
                short8 kf0 = *(const short8*)&Kl[(nt * 16 + l16) * 72 + quad * 8];
                short8 kf1 = *(const short8*)&Kl[(nt * 16 + l16) * 72 + 32 + quad * 8];
                S[nt] = __builtin_amdgcn_mfma_f32_16x16x32_bf16(qf0, kf0, S[nt], 0, 0, 0);
                S[nt] = __builtin_amdgcn_mfma_f32_16x16x32_bf16(qf1, kf1, S[nt], 0, 0, 0);
            }
#pragma unroll
            for (int nt = 0; nt < 4; ++nt)
#pragma unroll
                for (int r = 0; r < 4; ++r) {
                    bool live = (nt < wave) || (nt == wave && l16 <= quad * 4 + r);
                    float p = live ? __expf(S[nt][r]) : 0.f;
                    Pl[wave][(quad * 4 + r) * 72 + nt * 16 + l16] = f2bf(p);
                }
        }
#pragma unroll
        for (int kc = 0; kc < 2; ++kc) {
            short8 pf = *(const short8*)&Pl[wave][l16 * 72 + kc * 32 + quad * 8];
            lacc = __builtin_amdgcn_mfma_f32_16x16x32_bf16(pf, onesf, lacc, 0, 0, 0);
#pragma unroll
            for (int dt = 0; dt < 4; ++dt) {
                int d = dt * 16 + l16;
                int sh = ((2 * dt + (l16 >> 3)) & 3) * 16;
                int col = (kc * 32 + quad * 8 + sh) & 63;
                short8 vf = *(const short8*)&Vt[d * 72 + col];
                O[dt] = __builtin_amdgcn_mfma_f32_16x16x32_bf16(pf, vf, O[dt], 0, 0, 0);
            }
        }
    }
#pragma unroll
    for (int dt = 0; dt < 4; ++dt)
#pragma unroll
        for (int r = 0; r < 4; ++r) {
            int q = q0w + quad * 4 + r;
            float v = O[dt][r] / lacc[r];
            y[((size_t)(b * TS) + q) * EMB + h * 64 + dt * 16 + l16] = f2bf(v);
        }
}

// ---------------- host ---------------------------------------------------------
extern "C" void kernel_launch(void* const* d_in, const int* in_sizes, int n_in,
                              void* d_out, int out_size, void* d_ws, size_t ws_size,
                              hipStream_t stream)
{
    const int*  idx    = (const int*)d_in[0];
    const void* wte    = d_in[1];
    const void* wpe    = d_in[2];
    const void* attn_w = d_in[3];   // [L,512,1536]
    const void* proj_w = d_in[4];   // [L,512,512]
    const void* fc_w   = d_in[5];   // [L,512,2048]
    const void* fcp_w  = d_in[6];   // [L,2048,512]
    const void* ln1_w  = d_in[7];
    const void* ln2_w  = d_in[8];
    const void* lnf_w  = d_in[9];

    const size_t sz_xw    = (size_t)NTOK * EMB * 4;
    const size_t sz_hbf   = (size_t)NTOK * EMB * 2;
    const size_t sz_big   = (size_t)NTOK * 2048 * 2;
    const size_t sz_wteb  = (size_t)VPAD * EMB * 2;
    const size_t sz_wbuf1 = (size_t)3145728 * 2;
    const size_t need_legacy = 256 + sz_xw + sz_hbf + sz_big;
    const size_t need_fast   = need_legacy + sz_wteb + sz_wbuf1;
    const size_t need_all    = need_legacy + sz_wteb + NL * sz_wbuf1;   // ~80 MB

    if (ws_size < need_legacy) {
        sentinel_k<<<(out_size + 255) / 256, 256, 0, stream>>>((ushort_t*)d_out, out_size);
        return;
    }
    int* flag = (int*)d_ws;
    char* p = (char*)d_ws + 256;
    float*    xw  = (float*)p;    p += sz_xw;
    ushort_t* hbf = (ushort_t*)p; p += sz_hbf;
    ushort_t* big = (ushort_t*)p; p += sz_big;

    detect_k<<<1, 64, 0, stream>>>((const ushort_t*)wte, flag);
    embed_k<<<NTOK, 256, 0, stream>>>(idx, wte, wpe, xw, flag);

    if (ws_size >= need_fast) {
        ushort_t* wteb = (ushort_t*)p; p += sz_wteb;
        ushort_t* wbuf = (ushort_t*)p;
        const bool allw = (ws_size >= need_all);
        wconv_k<<<(VPAD * EMB + 255) / 256, 256, 0, stream>>>(wte, wteb,
                VPAD * EMB, VOCAB * EMB, flag);
        if (allw)
            wtrans_k<<<dim3(768, 1, NL), 256, 0, stream>>>(attn_w, proj_w, fc_w, fcp_w,
                    -1, wbuf, flag);
        for (int l = 0; l < NL; ++l) {
            ushort_t* wb = allw ? (wbuf + (size_t)l * 3145728) : wbuf;
            if (!allw)
                wtrans_k<<<dim3(768, 1, 1), 256, 0, stream>>>(attn_w, proj_w, fc_w, fcp_w,
                        (long)l, wbuf, flag);
            ln_k<<<NTOK / 4, 256, 0, stream>>>(xw, ln1_w, (long)l * EMB, hbf, flag);
            gemm_wide<<<dim3(24, 32), 256, 0, stream>>>(hbf, wb,
                    NTOK, 1536, 512, nullptr, big, nullptr, 0);
            attn_k<<<dim3(16, 32), 256, 0, stream>>>(big, hbf);
            gemm_nt<<<dim3(8, 64), 256, 0, stream>>>(hbf, wb + 786432,
                    NTOK, 512, 512, xw, nullptr, nullptr, xw, 0, flag);
            ln_k<<<NTOK / 4, 256, 0, stream>>>(xw, ln2_w, (long)l * EMB, hbf, flag);
            gemm_wide<<<dim3(32, 32), 256, 0, stream>>>(hbf, wb + 1048576,
                    NTOK, 2048, 512, nullptr, big, nullptr, 1 /*gelu*/);
            gemm_nt<<<dim3(8, 64), 256, 0, stream>>>(big, wb + 2097152,
                    NTOK, 512, 2048, xw, nullptr, nullptr, xw, 0, flag);
        }
        ln_k<<<NTOK / 4, 256, 0, stream>>>(xw, lnf_w, 0, hbf, flag);
        gemm_nt<<<dim3(6, 64), 256, 0, stream>>>(hbf, wteb,
                NTOK, VOCAB, 512, nullptr, nullptr, d_out, nullptr, 0, flag);
    } else {
        for (int l = 0; l < NL; ++l) {
            ln_k<<<NTOK / 4, 256, 0, stream>>>(xw, ln1_w, (long)l * EMB, hbf, flag);
            gemm_k<<<dim3(24, 64), 256, 0, stream>>>(hbf, attn_w, (long)l * 512 * 1536,
                    NTOK, 1536, 512, 0, nullptr, big, nullptr, nullptr, 0, flag);
            attn_k<<<dim3(16, 32), 256, 0, stream>>>(big, hbf);
            gemm_k<<<dim3(8, 64), 256, 0, stream>>>(hbf, proj_w, (long)l * 512 * 512,
                    NTOK, 512, 512, 0, xw, nullptr, nullptr, xw, 0, flag);
            ln_k<<<NTOK / 4, 256, 0, stream>>>(xw, ln2_w, (long)l * EMB, hbf, flag);
            gemm_k<<<dim3(32, 64), 256, 0, stream>>>(hbf, fc_w, (long)l * 512 * 2048,
                    NTOK, 2048, 512, 0, nullptr, big, nullptr, nullptr, 1, flag);
            gemm_k<<<dim3(8, 64), 256, 0, stream>>>(big, fcp_w, (long)l * 2048 * 512,
                    NTOK, 512, 2048, 0, xw, nullptr, nullptr, xw, 0, flag);
        }
        ln_k<<<NTOK / 4, 256, 0, stream>>>(xw, lnf_w, 0, hbf, flag);
        gemm_k<<<dim3(6, 64), 256, 0, stream>>>(hbf, wte, 0,
                NTOK, VOCAB, 512, 1, nullptr, nullptr, d_out, nullptr, 0, flag);
    }
}

// Round 5
// 1083.088 us; speedup vs baseline: 1.1768x; 1.0238x over previous
//
#include <hip/hip_runtime.h>

// GPT forward, MI355X gfx950.
// Shapes: V=371 E=512 H=8 L=8 B=4 T=1024 D=64, N=B*T=4096.
// Inputs float32 (runtime-detected, bf16 supported); output matches input fmt.
// r14: attn v6 — swapped QK^T (S^T = mfma(K,Q)) puts P lane-local along k;
// V columns stored sigma-permuted (p(k) = (nt>>1)*32 + qhat*8 + (nt&1)*4 + r)
// so PV B-fragments are the lane's OWN registers (zero shuffles, no P LDS).
// Removes per-tile 16x ds_write_u16 + 2x ds_read_b128 + 2 l-sum MFMAs; l-sum
// is now scalar + 2 shfl_xor at epilogue; O^T epilogue packs 8B stores.
// GEMMs/ln/wtrans unchanged from r13 (r9 structure + T14 prefetch).

#define VOCAB 371
#define VPAD  384
#define EMB   512
#define NH    8
#define NL    8
#define TS    1024
#define NTOK  4096
#define NEG_INF (-1e30f)

typedef unsigned short ushort_t;
typedef __attribute__((ext_vector_type(8))) short short8;
typedef __attribute__((ext_vector_type(4))) float f32x4;

__device__ inline float bf2f(ushort_t b) {
    unsigned int u = ((unsigned int)b) << 16;
    float f; __builtin_memcpy(&f, &u, 4); return f;
}
__device__ inline ushort_t f2bf(float f) {
    unsigned int u; __builtin_memcpy(&u, &f, 4);
    u = (u + 0x7fff + ((u >> 16) & 1)) >> 16;   // RNE
    return (ushort_t)u;
}

// ---------------- dtype probe ---------------------------------------------------
__global__ __launch_bounds__(64) void detect_k(const ushort_t* __restrict__ w,
        int* __restrict__ flag)
{
    int i = threadIdx.x;
    float v = bf2f(w[2 * i]);
    bool ok = (__builtin_fabsf(v) <= 4.0f);
    unsigned long long m = __ballot(ok);
    if (i == 0) flag[0] = (__popcll(m) >= 56) ? 1 : 0;   // 1 = bf16, 0 = float32
}

// ---------------- ws-too-small sentinel ----------------------------------------
__global__ __launch_bounds__(256) void sentinel_k(ushort_t* __restrict__ out, int n)
{
    int i = blockIdx.x * 256 + threadIdx.x;
    if (i < n) out[i] = 0x447A;
}

// ---------------- embedding ----------------------------------------------------
__global__ __launch_bounds__(256) void embed_k(const int* __restrict__ idx,
        const void* __restrict__ wte, const void* __restrict__ wpe,
        float* __restrict__ x, const int* __restrict__ flag)
{
    int n = blockIdx.x, tid = threadIdx.x;
    int t = n & (TS - 1);
    int v = idx[n];
    size_t o = (size_t)n * EMB;
    float a0, a1, b0, b1;
    if (*flag) {
        const ushort_t* te = (const ushort_t*)wte; const ushort_t* pe = (const ushort_t*)wpe;
        a0 = bf2f(te[v * EMB + tid]); a1 = bf2f(te[v * EMB + 256 + tid]);
        b0 = bf2f(pe[t * EMB + tid]); b1 = bf2f(pe[t * EMB + 256 + tid]);
    } else {
        const float* te = (const float*)wte; const float* pe = (const float*)wpe;
        a0 = te[v * EMB + tid]; a1 = te[v * EMB + 256 + tid];
        b0 = pe[t * EMB + tid]; b1 = pe[t * EMB + 256 + tid];
    }
    x[o + tid] = a0 + b0;
    x[o + 256 + tid] = a1 + b1;
}

// ---------------- layernorm v2: one wave per row, no barriers ------------------
__global__ __launch_bounds__(256) void ln_k(const float* __restrict__ x,
        const void* __restrict__ w, long woff, ushort_t* __restrict__ out,
        const int* __restrict__ flag)
{
    const int row = blockIdx.x * 4 + (threadIdx.x >> 6);
    const int lane = threadIdx.x & 63;
    const float* xr = x + (size_t)row * EMB + lane * 8;
    float4 f0 = *(const float4*)xr;
    float4 f1 = *(const float4*)(xr + 4);
    float v[8] = {f0.x, f0.y, f0.z, f0.w, f1.x, f1.y, f1.z, f1.w};
    float s = ((v[0] + v[1]) + (v[2] + v[3])) + ((v[4] + v[5]) + (v[6] + v[7]));
#pragma unroll
    for (int off = 32; off > 0; off >>= 1) s += __shfl_xor(s, off, 64);
    float mean = s * (1.0f / EMB);
    float s2 = 0.f;
#pragma unroll
    for (int j = 0; j < 8; ++j) { v[j] -= mean; s2 += v[j] * v[j]; }
#pragma unroll
    for (int off = 32; off > 0; off >>= 1) s2 += __shfl_xor(s2, off, 64);
    float rs = rsqrtf(s2 * (1.0f / EMB) + 1e-5f);
    float g[8];
    if (*flag) {
        const ushort_t* wb = (const ushort_t*)w + woff + lane * 8;
        ushort_t tmp[8];
        *(uint4*)tmp = *(const uint4*)wb;
#pragma unroll
        for (int j = 0; j < 8; ++j) g[j] = bf2f(tmp[j]);
    } else {
        const float* wf = (const float*)w + woff + lane * 8;
        float4 g0 = *(const float4*)wf;
        float4 g1 = *(const float4*)(wf + 4);
        g[0] = g0.x; g[1] = g0.y; g[2] = g0.z; g[3] = g0.w;
        g[4] = g1.x; g[5] = g1.y; g[6] = g1.z; g[7] = g1.w;
    }
    ushort_t ob[8];
#pragma unroll
    for (int j = 0; j < 8; ++j) ob[j] = f2bf(v[j] * rs * g[j]);
    *(uint4*)(out + (size_t)row * EMB + lane * 8) = *(uint4*)ob;
}

// ---------------- weight transpose v3: [K,N] dtype -> bf16 [N,K] ---------------
__global__ __launch_bounds__(256) void wtrans_k(const void* __restrict__ aw,
        const void* __restrict__ pw, const void* __restrict__ fw,
        const void* __restrict__ fpw, long l, ushort_t* __restrict__ wbuf,
        const int* __restrict__ flag)
{
    __shared__ float tile[64][65];
    const int isbf = *flag;
    long lay = (l < 0) ? (long)blockIdx.z : l;
    ushort_t* obase = wbuf + ((l < 0) ? (size_t)blockIdx.z * 3145728 : 0);
    int t = blockIdx.x;
    const void* src; ushort_t* dst; int Kw, Nw; long ioff;
    if (t < 192)      { src = aw;  dst = obase;           Kw = 512;  Nw = 1536; ioff = lay * 512L * 1536; }
    else if (t < 256) { t -= 192; src = pw;  dst = obase + 786432;  Kw = 512;  Nw = 512;  ioff = lay * 512L * 512; }
    else if (t < 512) { t -= 256; src = fw;  dst = obase + 1048576; Kw = 512;  Nw = 2048; ioff = lay * 512L * 2048; }
    else              { t -= 512; src = fpw; dst = obase + 2097152; Kw = 2048; Nw = 512;  ioff = lay * 2048L * 512; }
    int tn = Nw >> 6;
    int n0 = (t % tn) * 64, k0 = (t / tn) * 64;
    const int r = threadIdx.x >> 2, cq = (threadIdx.x & 3) * 16;
    size_t ii = ioff + (size_t)(k0 + r) * Nw + n0 + cq;
    if (isbf) {
        const ushort_t* sb = (const ushort_t*)src + ii;
        ushort_t tmp[16];
        *(uint4*)tmp = *(const uint4*)sb;
        *(uint4*)(tmp + 8) = *(const uint4*)(sb + 8);
#pragma unroll
        for (int j = 0; j < 16; ++j) tile[r][cq + j] = bf2f(tmp[j]);
    } else {
        const float* sf = (const float*)src + ii;
        *(float4*)&tile[r][cq]      = *(const float4*)sf;
        *(float4*)&tile[r][cq + 4]  = *(const float4*)(sf + 4);
        *(float4*)&tile[r][cq + 8]  = *(const float4*)(sf + 8);
        *(float4*)&tile[r][cq + 12] = *(const float4*)(sf + 12);
    }
    __syncthreads();
    const int kc = (threadIdx.x & 7) * 8;
#pragma unroll
    for (int j = 0; j < 2; ++j) {
        const int n = (threadIdx.x >> 3) + j * 32;
        unsigned pk[4];
#pragma unroll
        for (int i = 0; i < 4; ++i) {
            unsigned lo = f2bf(tile[kc + 2 * i][n]);
            unsigned hi = f2bf(tile[kc + 2 * i + 1][n]);
            pk[i] = lo | (hi << 16);
        }
        *(uint4*)(dst + (size_t)(n0 + n) * Kw + k0 + kc) = *(uint4*)pk;
    }
}

// ---------------- wte convert (zero-padded to VPAD rows) -----------------------
__global__ __launch_bounds__(256) void wconv_k(const void* __restrict__ in,
        ushort_t* __restrict__ out, int n, int nreal, const int* __restrict__ flag)
{
    int i = blockIdx.x * 256 + threadIdx.x;
    if (i >= n) return;
    ushort_t v = 0;
    if (i < nreal) v = (*flag) ? ((const ushort_t*)in)[i] : f2bf(((const float*)in)[i]);
    out[i] = v;
}

// ---------------- wide NT GEMM: 128x64 tile, BK=64 + T14 prefetch --------------
__global__ __launch_bounds__(256) void gemm_wide(const ushort_t* __restrict__ A,
        const ushort_t* __restrict__ Bt, int M, int N, int K,
        float* __restrict__ outF, ushort_t* __restrict__ outB,
        const float* __restrict__ res, int act)
{
    __shared__ ushort_t Al[128 * 72];
    __shared__ ushort_t Bl[64 * 72];
    const int tid = threadIdx.x;
    const int wave = tid >> 6, lane = tid & 63;
    const int quad = lane >> 4, l16 = lane & 15;
    const int m0 = blockIdx.y * 128, n0 = blockIdx.x * 64;
    const int ar = tid >> 1, ac = (tid & 1) * 32;
    const int br = tid >> 2, bc = (tid & 3) * 16;
    const ushort_t* Ag = A + (size_t)(m0 + ar) * K + ac;
    const ushort_t* Bg = Bt + (size_t)(n0 + br) * K + bc;
    f32x4 acc[2][4] = {};
    uint4 a0 = *(const uint4*)(Ag);
    uint4 a1 = *(const uint4*)(Ag + 8);
    uint4 a2 = *(const uint4*)(Ag + 16);
    uint4 a3 = *(const uint4*)(Ag + 24);
    uint4 b0 = *(const uint4*)(Bg);
    uint4 b1 = *(const uint4*)(Bg + 8);
    for (int k0 = 0; k0 < K; k0 += 64) {
        __syncthreads();
        *(uint4*)&Al[ar * 72 + ac]      = a0;
        *(uint4*)&Al[ar * 72 + ac + 8]  = a1;
        *(uint4*)&Al[ar * 72 + ac + 16] = a2;
        *(uint4*)&Al[ar * 72 + ac + 24] = a3;
        *(uint4*)&Bl[br * 72 + bc]     = b0;
        *(uint4*)&Bl[br * 72 + bc + 8] = b1;
        __syncthreads();
        if (k0 + 64 < K) {                      // prefetch: flies during MFMAs
            a0 = *(const uint4*)(Ag + k0 + 64);
            a1 = *(const uint4*)(Ag + k0 + 72);
            a2 = *(const uint4*)(Ag + k0 + 80);
            a3 = *(const uint4*)(Ag + k0 + 88);
            b0 = *(const uint4*)(Bg + k0 + 64);
            b1 = *(const uint4*)(Bg + k0 + 72);
        }
#pragma unroll
        for (int ks = 0; ks < 2; ++ks) {
            short8 af[2], bf[4];
#pragma unroll
            for (int mi = 0; mi < 2; ++mi)
                af[mi] = *(const short8*)&Al[(wave * 32 + mi * 16 + l16) * 72 + ks * 32 + quad * 8];
#pragma unroll
            for (int ni = 0; ni < 4; ++ni)
                bf[ni] = *(const short8*)&Bl[(ni * 16 + l16) * 72 + ks * 32 + quad * 8];
#pragma unroll
            for (int mi = 0; mi < 2; ++mi)
#pragma unroll
                for (int ni = 0; ni < 4; ++ni)
                    acc[mi][ni] = __builtin_amdgcn_mfma_f32_16x16x32_bf16(
                            af[mi], bf[ni], acc[mi][ni], 0, 0, 0);
        }
    }
#pragma unroll
    for (int mi = 0; mi < 2; ++mi) {
        const int rowb = m0 + wave * 32 + mi * 16 + quad * 4;
#pragma unroll
        for (int ni = 0; ni < 4; ++ni) {
            const int col = n0 + ni * 16 + l16;
#pragma unroll
            for (int r = 0; r < 4; ++r) {
                size_t o = (size_t)(rowb + r) * N + col;
                float v = acc[mi][ni][r];
                if (res) v += res[o];
                if (act) v = 0.5f * v * (1.0f + erff(v * 0.70710678118f));
                if (outF) outF[o] = v;
                else      outB[o] = f2bf(v);
            }
        }
    }
}

// ---------------- small NT GEMM (proj/fcp/logits) + T14 prefetch ---------------
__global__ __launch_bounds__(256) void gemm_nt(const ushort_t* __restrict__ A,
        const ushort_t* __restrict__ Bt, int M, int N, int K,
        float* __restrict__ outF, ushort_t* __restrict__ outB, void* __restrict__ outD,
        const float* __restrict__ res, int act, const int* __restrict__ flag)
{
    __shared__ ushort_t Al[64 * 72];
    __shared__ ushort_t Bl[64 * 72];
    const int isbf = *flag;
    const int tid = threadIdx.x;
    const int wave = tid >> 6, lane = tid & 63;
    const int quad = lane >> 4, l16 = lane & 15;
    const int m0 = blockIdx.y * 64, n0 = blockIdx.x * 64;
    const int sr = tid >> 2, sc = (tid & 3) * 16;
    const bool bok = (n0 + sr) < N;
    const ushort_t* Ag = A + (size_t)(m0 + sr) * K + sc;
    const ushort_t* Bg = Bt + (size_t)(n0 + sr) * K + sc;
    f32x4 acc[4] = {};
    uint4 a0 = *(const uint4*)(Ag);
    uint4 a1 = *(const uint4*)(Ag + 8);
    uint4 b0 = make_uint4(0, 0, 0, 0), b1 = make_uint4(0, 0, 0, 0);
    if (bok) { b0 = *(const uint4*)(Bg); b1 = *(const uint4*)(Bg + 8); }
    for (int k0 = 0; k0 < K; k0 += 64) {
        __syncthreads();
        *(uint4*)&Al[sr * 72 + sc] = a0; *(uint4*)&Al[sr * 72 + sc + 8] = a1;
        *(uint4*)&Bl[sr * 72 + sc] = b0; *(uint4*)&Bl[sr * 72 + sc + 8] = b1;
        __syncthreads();
        if (k0 + 64 < K) {                      // prefetch: flies during MFMAs
            a0 = *(const uint4*)(Ag + k0 + 64);
            a1 = *(const uint4*)(Ag + k0 + 72);
            if (bok) {
                b0 = *(const uint4*)(Bg + k0 + 64);
                b1 = *(const uint4*)(Bg + k0 + 72);
            }
        }
#pragma unroll
        for (int kc = 0; kc < 2; ++kc) {
            short8 af = *(const short8*)&Al[(wave * 16 + l16) * 72 + kc * 32 + quad * 8];
#pragma unroll
            for (int nt = 0; nt < 4; ++nt) {
                short8 bf = *(const short8*)&Bl[(nt * 16 + l16) * 72 + kc * 32 + quad * 8];
                acc[nt] = __builtin_amdgcn_mfma_f32_16x16x32_bf16(af, bf, acc[nt], 0, 0, 0);
            }
        }
    }
    const int mb = m0 + wave * 16 + quad * 4;
#pragma unroll
    for (int nt = 0; nt < 4; ++nt) {
        int nn = n0 + nt * 16 + l16;
        if (nn >= N) continue;
#pragma unroll
        for (int r = 0; r < 4; ++r) {
            size_t o = (size_t)(mb + r) * N + nn;
            float v = acc[nt][r];
            if (res) v += res[o];
            if (act) v = 0.5f * v * (1.0f + erff(v * 0.70710678118f));
            if (outF)      outF[o] = v;
            else if (outB) outB[o] = f2bf(v);
            else if (isbf) ((ushort_t*)outD)[o] = f2bf(v);
            else           ((float*)outD)[o] = v;
        }
    }
}

// ---------------- legacy GEMM (fallback) ---------------------------------------
__global__ __launch_bounds__(256) void gemm_k(const ushort_t* __restrict__ A,
        const void* __restrict__ B, long boff, int M, int N, int K, int bt,
        float* __restrict__ outF, ushort_t* __restrict__ outB, void* __restrict__ outD,
        const float* __restrict__ res, int act, const int* __restrict__ flag)
{
    __shared__ ushort_t Al[64 * 40];
    __shared__ ushort_t Bl[64 * 40];
    const int isbf = *flag;
    const int tid = threadIdx.x;
    const int wave = tid >> 6, lane = tid & 63;
    const int quad = lane >> 4, l16 = lane & 15;
    const int m0 = blockIdx.y * 64, n0 = blockIdx.x * 64;
    const int sr = tid >> 2, sc = (tid & 3) * 8;
    const int kr = tid >> 3, nc = (tid & 7) * 8;
    f32x4 acc[4] = {};
    const bool bok = (n0 + sr) < N;
    const ushort_t* Ag = A + (size_t)(m0 + sr) * K + sc;
    const ushort_t* Bb = (const ushort_t*)B + boff;
    const float*    Bf = (const float*)B + boff;
    const size_t i1 = (size_t)(n0 + sr) * K + sc;
    const size_t i0 = (size_t)kr * N + n0 + nc;
    for (int k0 = 0; k0 < K; k0 += 32) {
        uint4 av = *(const uint4*)(Ag + k0);
        ushort_t b8[8] = {0, 0, 0, 0, 0, 0, 0, 0};
        size_t bi = bt ? (i1 + k0) : (i0 + (size_t)k0 * N);
        if (!bt || bok) {
            if (isbf) *(uint4*)b8 = *(const uint4*)(Bb + bi);
            else {
                float4 f0 = *(const float4*)(Bf + bi);
                float4 f1 = *(const float4*)(Bf + bi + 4);
                b8[0] = f2bf(f0.x); b8[1] = f2bf(f0.y); b8[2] = f2bf(f0.z); b8[3] = f2bf(f0.w);
                b8[4] = f2bf(f1.x); b8[5] = f2bf(f1.y); b8[6] = f2bf(f1.z); b8[7] = f2bf(f1.w);
            }
        }
        __syncthreads();
        *(uint4*)&Al[sr * 40 + sc] = av;
        if (bt) *(uint4*)&Bl[sr * 40 + sc] = *(uint4*)b8;
        else {
#pragma unroll
            for (int i = 0; i < 8; ++i) Bl[(nc + i) * 40 + kr] = b8[i];
        }
        __syncthreads();
        short8 af = *(const short8*)&Al[(wave * 16 + l16) * 40 + quad * 8];
#pragma unroll
        for (int nt = 0; nt < 4; ++nt) {
            short8 bf = *(const short8*)&Bl[(nt * 16 + l16) * 40 + quad * 8];
            acc[nt] = __builtin_amdgcn_mfma_f32_16x16x32_bf16(af, bf, acc[nt], 0, 0, 0);
        }
    }
    const int mb = m0 + wave * 16 + quad * 4;
#pragma unroll
    for (int nt = 0; nt < 4; ++nt) {
        int nn = n0 + nt * 16 + l16;
        if (nn >= N) continue;
#pragma unroll
        for (int r = 0; r < 4; ++r) {
            size_t o = (size_t)(mb + r) * N + nn;
            float v = acc[nt][r];
            if (res) v += res[o];
            if (act) v = 0.5f * v * (1.0f + erff(v * 0.70710678118f));
            if (outF)      outF[o] = v;
            else if (outB) outB[o] = f2bf(v);
            else if (isbf) ((ushort_t*)outD)[o] = f2bf(v);
            else           ((float*)outD)[o] = v;
        }
    }
}

// ---------------- flash attention v6 (causal), in-register P -------------------
// Swapped QK^T: S^T = mfma(K_frag, Q_frag) -> lane (quad,l16) owns
// P^T[k = nt*16+quad*4+r][q = l16]. V columns stored sigma-permuted:
// p(k) = (nt>>1)*32 + qhat*8 + (nt&1)*4 + r  (qhat = (k>>2)&3), so the PV
// B-fragment words are the lane's own packed P: frag[j] = pk[2kc+(j>>1)][j&1].
// PV: O^T = mfma(V^T_frag, P_frag); output rows d = dt*16+quad*4+r, col q=l16.
// l-sum: scalar accumulation + 2 shfl_xor at epilogue. No P LDS, no l MFMAs.
__global__ __launch_bounds__(256) void attn_k(const ushort_t* __restrict__ qkv,
        ushort_t* __restrict__ y)
{
    __shared__ ushort_t Kl[64 * 72];
    __shared__ ushort_t Vt[64 * 72];
    const int tid = threadIdx.x, wave = tid >> 6, lane = tid & 63;
    const int quad = lane >> 4, l16 = lane & 15;
    const int qt = (int)gridDim.x - 1 - blockIdx.x;
    const int b = blockIdx.y >> 3, h = blockIdx.y & 7;
    const int q0b = qt * 64;
    const int q0w = q0b + wave * 16;
    const size_t rstr = 3 * EMB;
    const ushort_t* qbase = qkv + ((size_t)(b * TS) + q0w + l16) * rstr + h * 64;
    short8 qf0, qf1;
    {   // load Q and pre-scale by 1/8 (exact in bf16)
        ushort_t q0[8], q1[8];
        *(uint4*)q0 = *(const uint4*)(qbase + quad * 8);
        *(uint4*)q1 = *(const uint4*)(qbase + 32 + quad * 8);
#pragma unroll
        for (int i = 0; i < 8; ++i) {
            qf0[i] = (short)f2bf(bf2f(q0[i]) * 0.125f);
            qf1[i] = (short)f2bf(bf2f(q1[i]) * 0.125f);
        }
    }
    f32x4 O[4] = {};
    float lsum = 0.f;
    const int sk = tid >> 2, sdc = (tid & 3) * 16;
    const int vp = tid >> 3, vdc = (tid & 7) * 8;
    const int vsh = 16 * ((tid & 7) & 3);
    // sigma(2*vp): kc=vp>>4, qhat=(vp>>1)&3, ntlow=(vp>>3)&1, r=2*(vp&1)
    const int p0 = ((vp >> 4) << 5) | (((vp >> 1) & 3) << 3)
                 | (((vp >> 3) & 1) << 2) | ((vp & 1) << 1);
    const int vcol = (p0 + vsh) & 63;
    const ushort_t* kbase = qkv + ((size_t)(b * TS) + sk) * rstr + EMB + h * 64 + sdc;
    const ushort_t* vbase = qkv + ((size_t)(b * TS) + 2 * vp) * rstr + 2 * EMB + h * 64 + vdc;
    uint4 kv0 = *(const uint4*)(kbase);
    uint4 kv1 = *(const uint4*)(kbase + 8);
    uint4 vv0 = *(const uint4*)(vbase);
    uint4 vv1 = *(const uint4*)(vbase + rstr);
    for (int kt = 0; kt <= qt; ++kt) {
        __syncthreads();                 // all waves done reading Kl/Vt (prev)
        *(uint4*)&Kl[sk * 72 + sdc]     = kv0;
        *(uint4*)&Kl[sk * 72 + sdc + 8] = kv1;
        {
            ushort_t v0[8], v1[8];
            *(uint4*)v0 = vv0; *(uint4*)v1 = vv1;
#pragma unroll
            for (int i = 0; i < 8; ++i) {
                unsigned pk = (unsigned)v0[i] | ((unsigned)v1[i] << 16);
                *(unsigned*)&Vt[(vdc + i) * 72 + vcol] = pk;
            }
        }
        __syncthreads();                 // tile kt visible
        if (kt < qt) {                   // prefetch kt+1: flies during compute
            const size_t off = (size_t)(kt + 1) * 64 * rstr;
            kv0 = *(const uint4*)(kbase + off);
            kv1 = *(const uint4*)(kbase + off + 8);
            vv0 = *(const uint4*)(vbase + off);
            vv1 = *(const uint4*)(vbase + off + rstr);
        }
        const bool diag = (kt == qt);
        f32x4 S[4] = {};
#pragma unroll
        for (int nt = 0; nt < 4; ++nt) {
            if (diag && nt > wave) continue;
            short8 kf0 = *(const short8*)&Kl[(nt * 16 + l16) * 72 + quad * 8];
            short8 kf1 = *(const short8*)&Kl[(nt * 16 + l16) * 72 + 32 + quad * 8];
            S[nt] = __builtin_amdgcn_mfma_f32_16x16x32_bf16(kf0, qf0, S[nt], 0, 0, 0);
            S[nt] = __builtin_amdgcn_mfma_f32_16x16x32_bf16(kf1, qf1, S[nt], 0, 0, 0);
        }
        unsigned pk[4][2];
#pragma unroll
        for (int nt = 0; nt < 4; ++nt) {
            float p[4];
#pragma unroll
            for (int r = 0; r < 4; ++r) {
                bool live = !diag || (nt * 16 + quad * 4 + r <= wave * 16 + l16);
                p[r] = live ? __expf(S[nt][r]) : 0.f;
                lsum += p[r];
            }
            pk[nt][0] = (unsigned)f2bf(p[0]) | ((unsigned)f2bf(p[1]) << 16);
            pk[nt][1] = (unsigned)f2bf(p[2]) | ((unsigned)f2bf(p[3]) << 16);
        }
#pragma unroll
        for (int kc = 0; kc < 2; ++kc) {
            unsigned pw[4] = {pk[2 * kc][0], pk[2 * kc][1],
                              pk[2 * kc + 1][0], pk[2 * kc + 1][1]};
            short8 pf = *(const short8*)pw;
#pragma unroll
            for (int dt = 0; dt < 4; ++dt) {
                int d = dt * 16 + l16;
                int sh = ((2 * dt + (l16 >> 3)) & 3) * 16;
                int col = (kc * 32 + quad * 8 + sh) & 63;
                short8 vf = *(const short8*)&Vt[d * 72 + col];
                O[dt] = __builtin_amdgcn_mfma_f32_16x16x32_bf16(vf, pf, O[dt], 0, 0, 0);
            }
        }
    }
    lsum += __shfl_xor(lsum, 16, 64);
    lsum += __shfl_xor(lsum, 32, 64);
    const float inv = 1.0f / lsum;
    ushort_t* yb = y + ((size_t)(b * TS) + q0w + l16) * EMB + h * 64 + quad * 4;
#pragma unroll
    for (int dt = 0; dt < 4; ++dt) {
        unsigned ow[2];
        ow[0] = (unsigned)f2bf(O[dt][0] * inv) | ((unsigned)f2bf(O[dt][1] * inv) << 16);
        ow[1] = (unsigned)f2bf(O[dt][2] * inv) | ((unsigned)f2bf(O[dt][3] * inv) << 16);
        *(uint2*)(yb + dt * 16) = *(uint2*)ow;
    }
}

// ---------------- host ---------------------------------------------------------
extern "C" void kernel_launch(void* const* d_in, const int* in_sizes, int n_in,
                              void* d_out, int out_size, void* d_ws, size_t ws_size,
                              hipStream_t stream)
{
    const int*  idx    = (const int*)d_in[0];
    const void* wte    = d_in[1];
    const void* wpe    = d_in[2];
    const void* attn_w = d_in[3];   // [L,512,1536]
    const void* proj_w = d_in[4];   // [L,512,512]
    const void* fc_w   = d_in[5];   // [L,512,2048]
    const void* fcp_w  = d_in[6];   // [L,2048,512]
    const void* ln1_w  = d_in[7];
    const void* ln2_w  = d_in[8];
    const void* lnf_w  = d_in[9];

    const size_t sz_xw    = (size_t)NTOK * EMB * 4;
    const size_t sz_hbf   = (size_t)NTOK * EMB * 2;
    const size_t sz_big   = (size_t)NTOK * 2048 * 2;
    const size_t sz_wteb  = (size_t)VPAD * EMB * 2;
    const size_t sz_wbuf1 = (size_t)3145728 * 2;
    const size_t need_legacy = 256 + sz_xw + sz_hbf + sz_big;
    const size_t need_fast   = need_legacy + sz_wteb + sz_wbuf1;
    const size_t need_all    = need_legacy + sz_wteb + NL * sz_wbuf1;   // ~80 MB

    if (ws_size < need_legacy) {
        sentinel_k<<<(out_size + 255) / 256, 256, 0, stream>>>((ushort_t*)d_out, out_size);
        return;
    }
    int* flag = (int*)d_ws;
    char* p = (char*)d_ws + 256;
    float*    xw  = (float*)p;    p += sz_xw;
    ushort_t* hbf = (ushort_t*)p; p += sz_hbf;
    ushort_t* big = (ushort_t*)p; p += sz_big;

    detect_k<<<1, 64, 0, stream>>>((const ushort_t*)wte, flag);
    embed_k<<<NTOK, 256, 0, stream>>>(idx, wte, wpe, xw, flag);

    if (ws_size >= need_fast) {
        ushort_t* wteb = (ushort_t*)p; p += sz_wteb;
        ushort_t* wbuf = (ushort_t*)p;
        const bool allw = (ws_size >= need_all);
        wconv_k<<<(VPAD * EMB + 255) / 256, 256, 0, stream>>>(wte, wteb,
                VPAD * EMB, VOCAB * EMB, flag);
        if (allw)
            wtrans_k<<<dim3(768, 1, NL), 256, 0, stream>>>(attn_w, proj_w, fc_w, fcp_w,
                    -1, wbuf, flag);
        for (int l = 0; l < NL; ++l) {
            ushort_t* wb = allw ? (wbuf + (size_t)l * 3145728) : wbuf;
            if (!allw)
                wtrans_k<<<dim3(768, 1, 1), 256, 0, stream>>>(attn_w, proj_w, fc_w, fcp_w,
                        (long)l, wbuf, flag);
            ln_k<<<NTOK / 4, 256, 0, stream>>>(xw, ln1_w, (long)l * EMB, hbf, flag);
            gemm_wide<<<dim3(24, 32), 256, 0, stream>>>(hbf, wb,
                    NTOK, 1536, 512, nullptr, big, nullptr, 0);
            attn_k<<<dim3(16, 32), 256, 0, stream>>>(big, hbf);
            gemm_nt<<<dim3(8, 64), 256, 0, stream>>>(hbf, wb + 786432,
                    NTOK, 512, 512, xw, nullptr, nullptr, xw, 0, flag);
            ln_k<<<NTOK / 4, 256, 0, stream>>>(xw, ln2_w, (long)l * EMB, hbf, flag);
            gemm_wide<<<dim3(32, 32), 256, 0, stream>>>(hbf, wb + 1048576,
                    NTOK, 2048, 512, nullptr, big, nullptr, 1 /*gelu*/);
            gemm_nt<<<dim3(8, 64), 256, 0, stream>>>(big, wb + 2097152,
                    NTOK, 512, 2048, xw, nullptr, nullptr, xw, 0, flag);
        }
        ln_k<<<NTOK / 4, 256, 0, stream>>>(xw, lnf_w, 0, hbf, flag);
        gemm_nt<<<dim3(6, 64), 256, 0, stream>>>(hbf, wteb,
                NTOK, VOCAB, 512, nullptr, nullptr, d_out, nullptr, 0, flag);
    } else {
        for (int l = 0; l < NL; ++l) {
            ln_k<<<NTOK / 4, 256, 0, stream>>>(xw, ln1_w, (long)l * EMB, hbf, flag);
            gemm_k<<<dim3(24, 64), 256, 0, stream>>>(hbf, attn_w, (long)l * 512 * 1536,
                    NTOK, 1536, 512, 0, nullptr, big, nullptr, nullptr, 0, flag);
            attn_k<<<dim3(16, 32), 256, 0, stream>>>(big, hbf);
            gemm_k<<<dim3(8, 64), 256, 0, stream>>>(hbf, proj_w, (long)l * 512 * 512,
                    NTOK, 512, 512, 0, xw, nullptr, nullptr, xw, 0, flag);
            ln_k<<<NTOK / 4, 256, 0, stream>>>(xw, ln2_w, (long)l * EMB, hbf, flag);
            gemm_k<<<dim3(32, 64), 256, 0, stream>>>(hbf, fc_w, (long)l * 512 * 2048,
                    NTOK, 2048, 512, 0, nullptr, big, nullptr, nullptr, 1, flag);
            gemm_k<<<dim3(8, 64), 256, 0, stream>>>(big, fcp_w, (long)l * 2048 * 512,
                    NTOK, 512, 2048, 0, xw, nullptr, nullptr, xw, 0, flag);
        }
        ln_k<<<NTOK / 4, 256, 0, stream>>>(xw, lnf_w, 0, hbf, flag);
        gemm_k<<<dim3(6, 64), 256, 0, stream>>>(hbf, wte, 0,
                NTOK, VOCAB, 512, 1, nullptr, nullptr, d_out, nullptr, 0, flag);
    }
}